// Round 4
// baseline (500.102 us; speedup 1.0000x reference)
//
#include <hip/hip_runtime.h>
#include <math.h>

#define N_NODES    50000
#define N_EDGES_IN 800000
#define N_EDGES    850000   // + self loops
#define N_GRAPHS   512
#define NEG_SLOPE  0.2f
#define EPS_F      1e-16f

// ---------------- embedding gather: x[n] = emb[ids[n]] ----------------
__global__ void k_gather(const int* __restrict__ ids, const float4* __restrict__ emb,
                         float4* __restrict__ x) {
    int tid = blockIdx.x * blockDim.x + threadIdx.x;   // N_NODES * 32
    if (tid >= N_NODES * 32) return;
    int n = tid >> 5, c = tid & 31;
    x[n * 32 + c] = emb[ids[n] * 32 + c];
}

// ---------------- GEMM: h[N,128] = x[N,128] @ W[128,128] + fused scores -----
// block = 256 threads, 64 rows per block, full 128 cols.
// thread t: rows (t>>5)*8 .. +7, cols (t&31)*4 .. +3  (8x4 accumulator)
// epilogue additionally computes as_[r] = h[r]·a_src, ad_[r] = h[r]·a_dst
__global__ __launch_bounds__(256) void k_gemm(const float* __restrict__ x,
                                              const float* __restrict__ W,
                                              const float* __restrict__ a_s,
                                              const float* __restrict__ a_d,
                                              float* __restrict__ h,
                                              float* __restrict__ as_,
                                              float* __restrict__ ad_) {
    __shared__ float Ws[64 * 128];   // 32 KB  (one K-half)
    __shared__ float Xs[64 * 64];    // 16 KB
    int t = threadIdx.x;
    int row0 = blockIdx.x * 64;
    int g  = t >> 5;          // 0..7 row group
    int c4 = (t & 31) * 4;    // col start
    float acc[8][4] = {};
    for (int kc = 0; kc < 2; kc++) {
        // stage W rows [kc*64, kc*64+64) x 128  (2048 float4, 8/thread)
        {
            const float4* Wg = (const float4*)(W + kc * 64 * 128);
            float4* Wsv = (float4*)Ws;
            #pragma unroll
            for (int i = 0; i < 8; i++) Wsv[t + i * 256] = Wg[t + i * 256];
        }
        // stage X rows [row0, row0+64) cols [kc*64, +64)  (1024 float4, 4/thread)
        {
            float4* Xsv = (float4*)Xs;
            #pragma unroll
            for (int i = 0; i < 4; i++) {
                int j = t + i * 256;
                int r = j >> 4, cf = j & 15;
                int gr = row0 + r; if (gr >= N_NODES) gr = N_NODES - 1;
                Xsv[j] = ((const float4*)(x + (size_t)gr * 128 + kc * 64))[cf];
            }
        }
        __syncthreads();
        // k-blocked by 4: float4 LDS reads for X (2x fewer LDS ops), FMA-bound
        #pragma unroll 4
        for (int k4 = 0; k4 < 16; k4++) {
            const int kb = k4 * 4;
            float4 w0 = *(const float4*)&Ws[(kb + 0) * 128 + c4];
            float4 w1 = *(const float4*)&Ws[(kb + 1) * 128 + c4];
            float4 w2 = *(const float4*)&Ws[(kb + 2) * 128 + c4];
            float4 w3 = *(const float4*)&Ws[(kb + 3) * 128 + c4];
            #pragma unroll
            for (int i = 0; i < 8; i++) {
                float4 xv = *(const float4*)&Xs[(g * 8 + i) * 64 + kb];
                acc[i][0] += xv.x * w0.x + xv.y * w1.x + xv.z * w2.x + xv.w * w3.x;
                acc[i][1] += xv.x * w0.y + xv.y * w1.y + xv.z * w2.y + xv.w * w3.y;
                acc[i][2] += xv.x * w0.z + xv.y * w1.z + xv.z * w2.z + xv.w * w3.z;
                acc[i][3] += xv.x * w0.w + xv.y * w1.w + xv.z * w2.w + xv.w * w3.w;
            }
        }
        __syncthreads();
    }
    #pragma unroll
    for (int i = 0; i < 8; i++) {
        int r = row0 + g * 8 + i;
        if (r < N_NODES)
            *(float4*)&h[(size_t)r * 128 + c4] =
                make_float4(acc[i][0], acc[i][1], acc[i][2], acc[i][3]);
    }
    // fused scores: reduce acc·a over the 32 threads of each row group.
    float4 sa = *(const float4*)&a_s[c4];
    float4 da = *(const float4*)&a_d[c4];
    #pragma unroll
    for (int i = 0; i < 8; i++) {
        float ps = acc[i][0]*sa.x + acc[i][1]*sa.y + acc[i][2]*sa.z + acc[i][3]*sa.w;
        float pd = acc[i][0]*da.x + acc[i][1]*da.y + acc[i][2]*da.z + acc[i][3]*da.w;
        #pragma unroll
        for (int off = 16; off; off >>= 1) {
            ps += __shfl_xor(ps, off, 64);
            pd += __shfl_xor(pd, off, 64);
        }
        if ((t & 31) == 0) {
            int r = row0 + g * 8 + i;
            if (r < N_NODES) { as_[r] = ps; ad_[r] = pd; }
        }
    }
}

// ---------------- CSR build by dst ----------------
__global__ void k_hist(const int* __restrict__ ei, int* __restrict__ counts) {
    int e = blockIdx.x * blockDim.x + threadIdx.x;
    if (e >= N_EDGES) return;
    int d = (e < N_EDGES_IN) ? ei[N_EDGES_IN + e] : (e - N_EDGES_IN);
    atomicAdd(&counts[d], 1);
}

__global__ void k_scan1(const int* __restrict__ counts, int* __restrict__ row_ptr,
                        int* __restrict__ blksum) {
    __shared__ int s[256];
    int t = threadIdx.x, i = blockIdx.x * 256 + t;
    int v = (i < N_NODES) ? counts[i] : 0;
    s[t] = v; __syncthreads();
    for (int off = 1; off < 256; off <<= 1) {
        int x = (t >= off) ? s[t - off] : 0;
        __syncthreads(); s[t] += x; __syncthreads();
    }
    if (i < N_NODES) row_ptr[i] = s[t] - v;           // block-local exclusive
    if (t == 255) blksum[blockIdx.x] = s[255];
}

__global__ void k_scan2(int* __restrict__ blksum, int* __restrict__ row_ptr, int nb) {
    __shared__ int s[256];
    int t = threadIdx.x;
    int v = (t < nb) ? blksum[t] : 0;
    s[t] = v; __syncthreads();
    for (int off = 1; off < 256; off <<= 1) {
        int x = (t >= off) ? s[t - off] : 0;
        __syncthreads(); s[t] += x; __syncthreads();
    }
    if (t < nb) blksum[t] = s[t] - v;                 // exclusive block offsets
    if (t == 0) row_ptr[N_NODES] = N_EDGES;           // total is a compile-time constant
}

__global__ void k_scan3(int* __restrict__ row_ptr, const int* __restrict__ blksum) {
    int i = blockIdx.x * 256 + threadIdx.x;
    if (i < N_NODES) row_ptr[i] += blksum[blockIdx.x];
}

__global__ void k_scatter(const int* __restrict__ ei, const int* __restrict__ row_ptr,
                          int* __restrict__ fill, int* __restrict__ srcs) {
    int e = blockIdx.x * blockDim.x + threadIdx.x;
    if (e >= N_EDGES) return;
    int s, d;
    if (e < N_EDGES_IN) { s = ei[e]; d = ei[N_EDGES_IN + e]; }
    else                { s = e - N_EDGES_IN; d = s; }
    int pos = row_ptr[d] + atomicAdd(&fill[d], 1);
    srcs[pos] = s;
}

// ---------------- softmax + weighted aggregation, 16 lanes per dst ----------
// Each 16-lane group owns one dst; lane owns dims [gl*8, gl*8+8) (2 float4).
// Every edge is processed by all 16 lanes -> no cross-lane output merge.
// 4-edge unroll: 8 independent float4 loads in flight per lane.
__global__ __launch_bounds__(256) void k_aggregate(
        const float4* __restrict__ h4, const float* __restrict__ as_,
        const float* __restrict__ ad_, const int* __restrict__ row_ptr,
        const int* __restrict__ srcs, const float4* __restrict__ bias4,
        float4* __restrict__ xout, int do_relu) {
    int d = (blockIdx.x * blockDim.x + threadIdx.x) >> 4;
    if (d >= N_NODES) return;
    int lane = threadIdx.x & 63;
    int gl   = lane & 15;          // lane within 16-group
    int base = lane & 48;          // first lane of this group within the wave
    int lo = row_ptr[d], hi = row_ptr[d + 1];
    int deg = hi - lo;             // >= 1 (self-loop)
    float add = ad_[d];

    // pass A: online softmax stats, chunks of 16; cache first 4 chunks (deg<=64)
    float eC[4]; int sC[4];
    float m_l = -1e30f, s_l = 0.f;
    #pragma unroll
    for (int c = 0; c < 4; c++) {
        float e = -1e30f; int sidx = 0;
        int j = c * 16 + gl;
        if (j < deg) {
            sidx = srcs[lo + j];
            e = as_[sidx] + add;
            e = (e > 0.f) ? e : NEG_SLOPE * e;
            float nm = fmaxf(m_l, e);
            s_l = s_l * __expf(m_l - nm) + __expf(e - nm);
            m_l = nm;
        }
        eC[c] = e; sC[c] = sidx;
    }
    for (int j0 = 64; j0 < deg; j0 += 16) {   // rare (P(deg>64) ~ 0 at avg 17)
        int j = j0 + gl;
        if (j < deg) {
            int sidx = srcs[lo + j];
            float e = as_[sidx] + add;
            e = (e > 0.f) ? e : NEG_SLOPE * e;
            float nm = fmaxf(m_l, e);
            s_l = s_l * __expf(m_l - nm) + __expf(e - nm);
            m_l = nm;
        }
    }
    float m = m_l, s = s_l;
    #pragma unroll
    for (int off = 8; off; off >>= 1) {       // 16-lane reduction, 4 steps
        float om = __shfl_xor(m, off, 64);
        float os = __shfl_xor(s, off, 64);
        float nm = fmaxf(m, om);              // finite-sentinel: no inf-inf NaN
        s = s * __expf(m - nm) + os * __expf(om - nm);
        m = nm;
    }
    float inv = 1.f / (s + EPS_F);

    // pass B: accumulate alpha * h[src] into 8 dims per lane
    float4 acc0 = make_float4(0.f, 0.f, 0.f, 0.f);
    float4 acc1 = make_float4(0.f, 0.f, 0.f, 0.f);
    #pragma unroll
    for (int c = 0; c < 4; c++) {
        int j0 = c * 16;
        if (j0 >= deg) break;
        float w = __expf(eC[c] - m) * inv;    // invalid lanes: eC=-1e30 -> w=0
        int sidx = sC[c];
        int cnt = min(16, deg - j0);
        for (int jj = 0; jj < cnt; jj += 4) {
            // lanes >= cnt hold w=0, sidx=0 -> wasted lanes read row 0 (L1-hot)
            float w0 = __shfl(w, base + jj + 0, 64); int s0 = __shfl(sidx, base + jj + 0, 64);
            float w1 = __shfl(w, base + jj + 1, 64); int s1 = __shfl(sidx, base + jj + 1, 64);
            float w2 = __shfl(w, base + jj + 2, 64); int s2 = __shfl(sidx, base + jj + 2, 64);
            float w3 = __shfl(w, base + jj + 3, 64); int s3 = __shfl(sidx, base + jj + 3, 64);
            const float4* r0 = &h4[(size_t)s0 * 32 + gl * 2];
            const float4* r1 = &h4[(size_t)s1 * 32 + gl * 2];
            const float4* r2 = &h4[(size_t)s2 * 32 + gl * 2];
            const float4* r3 = &h4[(size_t)s3 * 32 + gl * 2];
            float4 a0 = r0[0], b0 = r0[1];
            float4 a1 = r1[0], b1 = r1[1];
            float4 a2 = r2[0], b2 = r2[1];
            float4 a3 = r3[0], b3 = r3[1];
            acc0.x += w0*a0.x; acc0.y += w0*a0.y; acc0.z += w0*a0.z; acc0.w += w0*a0.w;
            acc1.x += w0*b0.x; acc1.y += w0*b0.y; acc1.z += w0*b0.z; acc1.w += w0*b0.w;
            acc0.x += w1*a1.x; acc0.y += w1*a1.y; acc0.z += w1*a1.z; acc0.w += w1*a1.w;
            acc1.x += w1*b1.x; acc1.y += w1*b1.y; acc1.z += w1*b1.z; acc1.w += w1*b1.w;
            acc0.x += w2*a2.x; acc0.y += w2*a2.y; acc0.z += w2*a2.z; acc0.w += w2*a2.w;
            acc1.x += w2*b2.x; acc1.y += w2*b2.y; acc1.z += w2*b2.z; acc1.w += w2*b2.w;
            acc0.x += w3*a3.x; acc0.y += w3*a3.y; acc0.z += w3*a3.z; acc0.w += w3*a3.w;
            acc1.x += w3*b3.x; acc1.y += w3*b3.y; acc1.z += w3*b3.z; acc1.w += w3*b3.w;
        }
    }
    for (int j0 = 64; j0 < deg; j0 += 16) {   // rare tail
        int j = j0 + gl;
        float w = 0.f; int sidx = 0;
        if (j < deg) {
            int si = srcs[lo + j];
            float e = as_[si] + add;
            e = (e > 0.f) ? e : NEG_SLOPE * e;
            w = __expf(e - m) * inv;
            sidx = si;
        }
        int cnt = min(16, deg - j0);
        for (int jj = 0; jj < cnt; jj += 4) {
            float w0 = __shfl(w, base + jj + 0, 64); int s0 = __shfl(sidx, base + jj + 0, 64);
            float w1 = __shfl(w, base + jj + 1, 64); int s1 = __shfl(sidx, base + jj + 1, 64);
            float w2 = __shfl(w, base + jj + 2, 64); int s2 = __shfl(sidx, base + jj + 2, 64);
            float w3 = __shfl(w, base + jj + 3, 64); int s3 = __shfl(sidx, base + jj + 3, 64);
            const float4* r0 = &h4[(size_t)s0 * 32 + gl * 2];
            const float4* r1 = &h4[(size_t)s1 * 32 + gl * 2];
            const float4* r2 = &h4[(size_t)s2 * 32 + gl * 2];
            const float4* r3 = &h4[(size_t)s3 * 32 + gl * 2];
            float4 a0 = r0[0], b0 = r0[1];
            float4 a1 = r1[0], b1 = r1[1];
            float4 a2 = r2[0], b2 = r2[1];
            float4 a3 = r3[0], b3 = r3[1];
            acc0.x += w0*a0.x; acc0.y += w0*a0.y; acc0.z += w0*a0.z; acc0.w += w0*a0.w;
            acc1.x += w0*b0.x; acc1.y += w0*b0.y; acc1.z += w0*b0.z; acc1.w += w0*b0.w;
            acc0.x += w1*a1.x; acc0.y += w1*a1.y; acc0.z += w1*a1.z; acc0.w += w1*a1.w;
            acc1.x += w1*b1.x; acc1.y += w1*b1.y; acc1.z += w1*b1.z; acc1.w += w1*b1.w;
            acc0.x += w2*a2.x; acc0.y += w2*a2.y; acc0.z += w2*a2.z; acc0.w += w2*a2.w;
            acc1.x += w2*b2.x; acc1.y += w2*b2.y; acc1.z += w2*b2.z; acc1.w += w2*b2.w;
            acc0.x += w3*a3.x; acc0.y += w3*a3.y; acc0.z += w3*a3.z; acc0.w += w3*a3.w;
            acc1.x += w3*b3.x; acc1.y += w3*b3.y; acc1.z += w3*b3.z; acc1.w += w3*b3.w;
        }
    }
    float4 b0 = bias4[gl * 2], b1 = bias4[gl * 2 + 1];
    float4 o0 = make_float4(acc0.x + b0.x, acc0.y + b0.y, acc0.z + b0.z, acc0.w + b0.w);
    float4 o1 = make_float4(acc1.x + b1.x, acc1.y + b1.y, acc1.z + b1.z, acc1.w + b1.w);
    if (do_relu) {
        o0.x = fmaxf(o0.x, 0.f); o0.y = fmaxf(o0.y, 0.f);
        o0.z = fmaxf(o0.z, 0.f); o0.w = fmaxf(o0.w, 0.f);
        o1.x = fmaxf(o1.x, 0.f); o1.y = fmaxf(o1.y, 0.f);
        o1.z = fmaxf(o1.z, 0.f); o1.w = fmaxf(o1.w, 0.f);
    }
    xout[(size_t)d * 32 + gl * 2]     = o0;
    xout[(size_t)d * 32 + gl * 2 + 1] = o1;
}

// ---------------- global mean pool (batch is sorted) ----------------
__global__ __launch_bounds__(512) void k_pool(const float* __restrict__ x,
                                              const int* __restrict__ batch,
                                              float* __restrict__ out) {
    __shared__ float red[512];
    __shared__ int sh[2];
    int g = blockIdx.x;
    int t = threadIdx.x;   // 512 = 4 rows x 128 dims
    if (t == 0) {
        int lo = 0, hi = N_NODES;
        while (lo < hi) { int mid = (lo + hi) >> 1; if (batch[mid] < g) lo = mid + 1; else hi = mid; }
        sh[0] = lo;
        int lo2 = lo, hi2 = N_NODES;
        while (lo2 < hi2) { int mid = (lo2 + hi2) >> 1; if (batch[mid] < g + 1) lo2 = mid + 1; else hi2 = mid; }
        sh[1] = lo2;
    }
    __syncthreads();
    int lo = sh[0], hi = sh[1];
    int sub = t >> 7, dim = t & 127;
    float sum = 0.f;
    for (int i = lo + sub; i < hi; i += 4) sum += x[(size_t)i * 128 + dim];
    red[t] = sum;
    __syncthreads();
    if (t < 128) {
        float s = red[t] + red[t + 128] + red[t + 256] + red[t + 384];
        int cnt = hi - lo;
        out[g * 128 + t] = s * (cnt > 0 ? 1.f / (float)cnt : 1.f);
    }
}

extern "C" void kernel_launch(void* const* d_in, const int* in_sizes, int n_in,
                              void* d_out, int out_size, void* d_ws, size_t ws_size,
                              hipStream_t stream) {
    const int*   node_ids   = (const int*)d_in[0];
    const int*   edge_index = (const int*)d_in[1];   // [2][800000]
    const int*   batch      = (const int*)d_in[2];
    const float* emb        = (const float*)d_in[3];
    const float* W[3]  = {(const float*)d_in[4],  (const float*)d_in[8],  (const float*)d_in[12]};
    const float* As[3] = {(const float*)d_in[5],  (const float*)d_in[9],  (const float*)d_in[13]};
    const float* Ad[3] = {(const float*)d_in[6],  (const float*)d_in[10], (const float*)d_in[14]};
    const float* Bs[3] = {(const float*)d_in[7],  (const float*)d_in[11], (const float*)d_in[15]};

    char* ws = (char*)d_ws;
    size_t off = 0;
    auto alloc = [&](size_t bytes) {
        void* p = ws + off; off += (bytes + 255) & ~(size_t)255; return p;
    };
    float* xA      = (float*)alloc((size_t)N_NODES * 128 * 4);  // current x
    float* xB      = (float*)alloc((size_t)N_NODES * 128 * 4);  // h
    float* as_     = (float*)alloc((size_t)N_NODES * 4);
    float* ad_     = (float*)alloc((size_t)N_NODES * 4);
    int*   counts  = (int*)alloc((size_t)N_NODES * 4);
    int*   fill    = (int*)alloc((size_t)N_NODES * 4);
    int*   row_ptr = (int*)alloc((size_t)(N_NODES + 1) * 4);
    int*   blksum  = (int*)alloc(256 * 4);
    int*   srcs    = (int*)alloc((size_t)N_EDGES * 4);
    (void)ws_size; (void)in_sizes; (void)n_in; (void)out_size;

    hipMemsetAsync(counts, 0, (size_t)N_NODES * 4, stream);
    hipMemsetAsync(fill,   0, (size_t)N_NODES * 4, stream);

    // CSR by dst (shared by all 3 layers)
    int ebl = (N_EDGES + 255) / 256;
    int nb  = (N_NODES + 255) / 256;   // 196
    k_hist   <<<ebl, 256, 0, stream>>>(edge_index, counts);
    k_scan1  <<<nb, 256, 0, stream>>>(counts, row_ptr, blksum);
    k_scan2  <<<1, 256, 0, stream>>>(blksum, row_ptr, nb);
    k_scan3  <<<nb, 256, 0, stream>>>(row_ptr, blksum);
    k_scatter<<<ebl, 256, 0, stream>>>(edge_index, row_ptr, fill, srcs);

    // x0 = emb[node_ids]
    k_gather<<<(N_NODES * 32 + 255) / 256, 256, 0, stream>>>(node_ids, (const float4*)emb, (float4*)xA);

    for (int l = 0; l < 3; l++) {
        k_gemm<<<(N_NODES + 63) / 64, 256, 0, stream>>>(xA, W[l], As[l], Ad[l], xB, as_, ad_);
        k_aggregate<<<(N_NODES * 16 + 255) / 256, 256, 0, stream>>>((const float4*)xB,
                 as_, ad_, row_ptr, srcs, (const float4*)Bs[l], (float4*)xA,
                 (l < 2) ? 1 : 0);
    }
    k_pool<<<N_GRAPHS, 512, 0, stream>>>(xA, batch, (float*)d_out);
}

// Round 5
// 475.649 us; speedup vs baseline: 1.0514x; 1.0514x over previous
//
#include <hip/hip_runtime.h>
#include <math.h>

#define N_NODES    50000
#define N_EDGES_IN 800000
#define N_EDGES    850000   // + self loops
#define N_GRAPHS   512
#define NEG_SLOPE  0.2f
#define EPS_F      1e-16f

// ---------------- GEMM: h[N,128] = x[N,128] @ W[128,128] + fused scores -----
// 128x128 tile, 256 threads, 8x8 micro-tile. Thread (tr,tc), tr=t>>4, tc=t&15:
// rows {row0 + (h)*64 + tr*4 + i}, cols {(h)*64 + tc*4 + j} for h in {0,1}.
// Split row/col halves make every LDS b128 read conflict-light (<=2-way).
// Xs is transposed ([k][row]) so per-k row reads are contiguous b128.
// Optional ids: X row r is read from xsrc[ids[r]] (fuses embedding gather).
__global__ __launch_bounds__(256) void k_gemm(const float* __restrict__ xsrc,
                                              const int* __restrict__ ids,
                                              const float* __restrict__ W,
                                              const float* __restrict__ a_s,
                                              const float* __restrict__ a_d,
                                              float* __restrict__ h,
                                              float* __restrict__ as_,
                                              float* __restrict__ ad_) {
    __shared__ float Xs[32][132];   // [k][row], pad 132 (16B-aligned rows, banks spread)
    __shared__ float Ws[32][128];   // [k][col]
    int t = threadIdx.x;
    int tr = t >> 4, tc = t & 15;
    int row0 = blockIdx.x * 128;
    float acc[8][8] = {};
    for (int kc = 0; kc < 4; kc++) {
        // stage X: 128 rows x 32 k = 1024 float4, 4/thread; transpose into Xs
        #pragma unroll
        for (int i = 0; i < 4; i++) {
            int q = t + i * 256;
            int r = q >> 3, cf = q & 7;
            int gr = row0 + r; if (gr >= N_NODES) gr = N_NODES - 1;
            int srow = ids ? ids[gr] : gr;
            float4 v = ((const float4*)(xsrc + (size_t)srow * 128 + kc * 32))[cf];
            Xs[cf * 4 + 0][r] = v.x;
            Xs[cf * 4 + 1][r] = v.y;
            Xs[cf * 4 + 2][r] = v.z;
            Xs[cf * 4 + 3][r] = v.w;
        }
        // stage W: 32 k x 128 cols = 1024 float4, 4/thread, linear
        #pragma unroll
        for (int i = 0; i < 4; i++) {
            int q = t + i * 256;
            int kl = q >> 5, cf = q & 31;
            ((float4*)&Ws[kl][0])[cf] =
                ((const float4*)(W + (size_t)(kc * 32 + kl) * 128))[cf];
        }
        __syncthreads();
        #pragma unroll 4
        for (int k = 0; k < 32; k++) {
            float4 xa = *(const float4*)&Xs[k][tr * 4];
            float4 xb = *(const float4*)&Xs[k][64 + tr * 4];
            float4 wa = *(const float4*)&Ws[k][tc * 4];
            float4 wb = *(const float4*)&Ws[k][64 + tc * 4];
            float xr[8] = {xa.x, xa.y, xa.z, xa.w, xb.x, xb.y, xb.z, xb.w};
            float wc[8] = {wa.x, wa.y, wa.z, wa.w, wb.x, wb.y, wb.z, wb.w};
            #pragma unroll
            for (int i2 = 0; i2 < 8; i2++)
                #pragma unroll
                for (int j2 = 0; j2 < 8; j2++)
                    acc[i2][j2] += xr[i2] * wc[j2];
        }
        __syncthreads();
    }
    // epilogue: h stores + fused scores
    float4 saa = *(const float4*)&a_s[tc * 4], sab = *(const float4*)&a_s[64 + tc * 4];
    float4 daa = *(const float4*)&a_d[tc * 4], dab = *(const float4*)&a_d[64 + tc * 4];
    float sav[8] = {saa.x, saa.y, saa.z, saa.w, sab.x, sab.y, sab.z, sab.w};
    float dav[8] = {daa.x, daa.y, daa.z, daa.w, dab.x, dab.y, dab.z, dab.w};
    #pragma unroll
    for (int ri = 0; ri < 8; ri++) {
        int row = row0 + (ri >> 2) * 64 + tr * 4 + (ri & 3);
        bool ok = row < N_NODES;
        if (ok) {
            *(float4*)&h[(size_t)row * 128 + tc * 4] =
                make_float4(acc[ri][0], acc[ri][1], acc[ri][2], acc[ri][3]);
            *(float4*)&h[(size_t)row * 128 + 64 + tc * 4] =
                make_float4(acc[ri][4], acc[ri][5], acc[ri][6], acc[ri][7]);
        }
        float ps = 0.f, pd = 0.f;
        #pragma unroll
        for (int j2 = 0; j2 < 8; j2++) { ps += acc[ri][j2] * sav[j2]; pd += acc[ri][j2] * dav[j2]; }
        #pragma unroll
        for (int off = 8; off; off >>= 1) {   // reduce across the 16 tc lanes
            ps += __shfl_xor(ps, off, 64);
            pd += __shfl_xor(pd, off, 64);
        }
        if (ok && tc == 0) { as_[row] = ps; ad_[row] = pd; }
    }
}

// ---------------- CSR build by dst ----------------
__global__ void k_hist(const int* __restrict__ ei, int* __restrict__ counts) {
    int e = blockIdx.x * blockDim.x + threadIdx.x;
    if (e >= N_EDGES) return;
    int d = (e < N_EDGES_IN) ? ei[N_EDGES_IN + e] : (e - N_EDGES_IN);
    atomicAdd(&counts[d], 1);
}

__global__ void k_scan1(const int* __restrict__ counts, int* __restrict__ row_ptr,
                        int* __restrict__ blksum) {
    __shared__ int s[256];
    int t = threadIdx.x, i = blockIdx.x * 256 + t;
    int v = (i < N_NODES) ? counts[i] : 0;
    s[t] = v; __syncthreads();
    for (int off = 1; off < 256; off <<= 1) {
        int x = (t >= off) ? s[t - off] : 0;
        __syncthreads(); s[t] += x; __syncthreads();
    }
    if (i < N_NODES) row_ptr[i] = s[t] - v;           // block-local exclusive
    if (t == 255) blksum[blockIdx.x] = s[255];
}

__global__ void k_scan2(int* __restrict__ blksum, int* __restrict__ row_ptr, int nb) {
    __shared__ int s[256];
    int t = threadIdx.x;
    int v = (t < nb) ? blksum[t] : 0;
    s[t] = v; __syncthreads();
    for (int off = 1; off < 256; off <<= 1) {
        int x = (t >= off) ? s[t - off] : 0;
        __syncthreads(); s[t] += x; __syncthreads();
    }
    if (t < nb) blksum[t] = s[t] - v;                 // exclusive block offsets
    if (t == 0) row_ptr[N_NODES] = N_EDGES;           // total is a compile-time constant
}

__global__ void k_scan3(int* __restrict__ row_ptr, const int* __restrict__ blksum) {
    int i = blockIdx.x * 256 + threadIdx.x;
    if (i < N_NODES) row_ptr[i] += blksum[blockIdx.x];
}

__global__ void k_scatter(const int* __restrict__ ei, const int* __restrict__ row_ptr,
                          int* __restrict__ fill, int* __restrict__ srcs) {
    int e = blockIdx.x * blockDim.x + threadIdx.x;
    if (e >= N_EDGES) return;
    int s, d;
    if (e < N_EDGES_IN) { s = ei[e]; d = ei[N_EDGES_IN + e]; }
    else                { s = e - N_EDGES_IN; d = s; }
    int pos = row_ptr[d] + atomicAdd(&fill[d], 1);
    srcs[pos] = s;
}

// ---------------- softmax + weighted aggregation, 16 lanes per dst ----------
// (R4 structure — measured at its memory-path floor; unchanged)
__global__ __launch_bounds__(256) void k_aggregate(
        const float4* __restrict__ h4, const float* __restrict__ as_,
        const float* __restrict__ ad_, const int* __restrict__ row_ptr,
        const int* __restrict__ srcs, const float4* __restrict__ bias4,
        float4* __restrict__ xout, int do_relu) {
    int d = (blockIdx.x * blockDim.x + threadIdx.x) >> 4;
    if (d >= N_NODES) return;
    int lane = threadIdx.x & 63;
    int gl   = lane & 15;          // lane within 16-group
    int base = lane & 48;          // first lane of this group within the wave
    int lo = row_ptr[d], hi = row_ptr[d + 1];
    int deg = hi - lo;             // >= 1 (self-loop)
    float add = ad_[d];

    // pass A: online softmax stats, chunks of 16; cache first 4 chunks (deg<=64)
    float eC[4]; int sC[4];
    float m_l = -1e30f, s_l = 0.f;
    #pragma unroll
    for (int c = 0; c < 4; c++) {
        float e = -1e30f; int sidx = 0;
        int j = c * 16 + gl;
        if (j < deg) {
            sidx = srcs[lo + j];
            e = as_[sidx] + add;
            e = (e > 0.f) ? e : NEG_SLOPE * e;
            float nm = fmaxf(m_l, e);
            s_l = s_l * __expf(m_l - nm) + __expf(e - nm);
            m_l = nm;
        }
        eC[c] = e; sC[c] = sidx;
    }
    for (int j0 = 64; j0 < deg; j0 += 16) {   // rare (P(deg>64) ~ 0 at avg 17)
        int j = j0 + gl;
        if (j < deg) {
            int sidx = srcs[lo + j];
            float e = as_[sidx] + add;
            e = (e > 0.f) ? e : NEG_SLOPE * e;
            float nm = fmaxf(m_l, e);
            s_l = s_l * __expf(m_l - nm) + __expf(e - nm);
            m_l = nm;
        }
    }
    float m = m_l, s = s_l;
    #pragma unroll
    for (int off = 8; off; off >>= 1) {       // 16-lane reduction, 4 steps
        float om = __shfl_xor(m, off, 64);
        float os = __shfl_xor(s, off, 64);
        float nm = fmaxf(m, om);              // finite-sentinel: no inf-inf NaN
        s = s * __expf(m - nm) + os * __expf(om - nm);
        m = nm;
    }
    float inv = 1.f / (s + EPS_F);

    // pass B: accumulate alpha * h[src] into 8 dims per lane
    float4 acc0 = make_float4(0.f, 0.f, 0.f, 0.f);
    float4 acc1 = make_float4(0.f, 0.f, 0.f, 0.f);
    #pragma unroll
    for (int c = 0; c < 4; c++) {
        int j0 = c * 16;
        if (j0 >= deg) break;
        float w = __expf(eC[c] - m) * inv;    // invalid lanes: eC=-1e30 -> w=0
        int sidx = sC[c];
        int cnt = min(16, deg - j0);
        for (int jj = 0; jj < cnt; jj += 4) {
            float w0 = __shfl(w, base + jj + 0, 64); int s0 = __shfl(sidx, base + jj + 0, 64);
            float w1 = __shfl(w, base + jj + 1, 64); int s1 = __shfl(sidx, base + jj + 1, 64);
            float w2 = __shfl(w, base + jj + 2, 64); int s2 = __shfl(sidx, base + jj + 2, 64);
            float w3 = __shfl(w, base + jj + 3, 64); int s3 = __shfl(sidx, base + jj + 3, 64);
            const float4* r0 = &h4[(size_t)s0 * 32 + gl * 2];
            const float4* r1 = &h4[(size_t)s1 * 32 + gl * 2];
            const float4* r2 = &h4[(size_t)s2 * 32 + gl * 2];
            const float4* r3 = &h4[(size_t)s3 * 32 + gl * 2];
            float4 a0 = r0[0], b0 = r0[1];
            float4 a1 = r1[0], b1 = r1[1];
            float4 a2 = r2[0], b2 = r2[1];
            float4 a3 = r3[0], b3 = r3[1];
            acc0.x += w0*a0.x; acc0.y += w0*a0.y; acc0.z += w0*a0.z; acc0.w += w0*a0.w;
            acc1.x += w0*b0.x; acc1.y += w0*b0.y; acc1.z += w0*b0.z; acc1.w += w0*b0.w;
            acc0.x += w1*a1.x; acc0.y += w1*a1.y; acc0.z += w1*a1.z; acc0.w += w1*a1.w;
            acc1.x += w1*b1.x; acc1.y += w1*b1.y; acc1.z += w1*b1.z; acc1.w += w1*b1.w;
            acc0.x += w2*a2.x; acc0.y += w2*a2.y; acc0.z += w2*a2.z; acc0.w += w2*a2.w;
            acc1.x += w2*b2.x; acc1.y += w2*b2.y; acc1.z += w2*b2.z; acc1.w += w2*b2.w;
            acc0.x += w3*a3.x; acc0.y += w3*a3.y; acc0.z += w3*a3.z; acc0.w += w3*a3.w;
            acc1.x += w3*b3.x; acc1.y += w3*b3.y; acc1.z += w3*b3.z; acc1.w += w3*b3.w;
        }
    }
    for (int j0 = 64; j0 < deg; j0 += 16) {   // rare tail
        int j = j0 + gl;
        float w = 0.f; int sidx = 0;
        if (j < deg) {
            int si = srcs[lo + j];
            float e = as_[si] + add;
            e = (e > 0.f) ? e : NEG_SLOPE * e;
            w = __expf(e - m) * inv;
            sidx = si;
        }
        int cnt = min(16, deg - j0);
        for (int jj = 0; jj < cnt; jj += 4) {
            float w0 = __shfl(w, base + jj + 0, 64); int s0 = __shfl(sidx, base + jj + 0, 64);
            float w1 = __shfl(w, base + jj + 1, 64); int s1 = __shfl(sidx, base + jj + 1, 64);
            float w2 = __shfl(w, base + jj + 2, 64); int s2 = __shfl(sidx, base + jj + 2, 64);
            float w3 = __shfl(w, base + jj + 3, 64); int s3 = __shfl(sidx, base + jj + 3, 64);
            const float4* r0 = &h4[(size_t)s0 * 32 + gl * 2];
            const float4* r1 = &h4[(size_t)s1 * 32 + gl * 2];
            const float4* r2 = &h4[(size_t)s2 * 32 + gl * 2];
            const float4* r3 = &h4[(size_t)s3 * 32 + gl * 2];
            float4 a0 = r0[0], b0 = r0[1];
            float4 a1 = r1[0], b1 = r1[1];
            float4 a2 = r2[0], b2 = r2[1];
            float4 a3 = r3[0], b3 = r3[1];
            acc0.x += w0*a0.x; acc0.y += w0*a0.y; acc0.z += w0*a0.z; acc0.w += w0*a0.w;
            acc1.x += w0*b0.x; acc1.y += w0*b0.y; acc1.z += w0*b0.z; acc1.w += w0*b0.w;
            acc0.x += w1*a1.x; acc0.y += w1*a1.y; acc0.z += w1*a1.z; acc0.w += w1*a1.w;
            acc1.x += w1*b1.x; acc1.y += w1*b1.y; acc1.z += w1*b1.z; acc1.w += w1*b1.w;
            acc0.x += w2*a2.x; acc0.y += w2*a2.y; acc0.z += w2*a2.z; acc0.w += w2*a2.w;
            acc1.x += w2*b2.x; acc1.y += w2*b2.y; acc1.z += w2*b2.z; acc1.w += w2*b2.w;
            acc0.x += w3*a3.x; acc0.y += w3*a3.y; acc0.z += w3*a3.z; acc0.w += w3*a3.w;
            acc1.x += w3*b3.x; acc1.y += w3*b3.y; acc1.z += w3*b3.z; acc1.w += w3*b3.w;
        }
    }
    float4 b0 = bias4[gl * 2], b1 = bias4[gl * 2 + 1];
    float4 o0 = make_float4(acc0.x + b0.x, acc0.y + b0.y, acc0.z + b0.z, acc0.w + b0.w);
    float4 o1 = make_float4(acc1.x + b1.x, acc1.y + b1.y, acc1.z + b1.z, acc1.w + b1.w);
    if (do_relu) {
        o0.x = fmaxf(o0.x, 0.f); o0.y = fmaxf(o0.y, 0.f);
        o0.z = fmaxf(o0.z, 0.f); o0.w = fmaxf(o0.w, 0.f);
        o1.x = fmaxf(o1.x, 0.f); o1.y = fmaxf(o1.y, 0.f);
        o1.z = fmaxf(o1.z, 0.f); o1.w = fmaxf(o1.w, 0.f);
    }
    xout[(size_t)d * 32 + gl * 2]     = o0;
    xout[(size_t)d * 32 + gl * 2 + 1] = o1;
}

// ---------------- global mean pool (batch is sorted) ----------------
__global__ __launch_bounds__(512) void k_pool(const float* __restrict__ x,
                                              const int* __restrict__ batch,
                                              float* __restrict__ out) {
    __shared__ float red[512];
    __shared__ int sh[2];
    int g = blockIdx.x;
    int t = threadIdx.x;   // 512 = 4 rows x 128 dims
    if (t == 0) {
        int lo = 0, hi = N_NODES;
        while (lo < hi) { int mid = (lo + hi) >> 1; if (batch[mid] < g) lo = mid + 1; else hi = mid; }
        sh[0] = lo;
        int lo2 = lo, hi2 = N_NODES;
        while (lo2 < hi2) { int mid = (lo2 + hi2) >> 1; if (batch[mid] < g + 1) lo2 = mid + 1; else hi2 = mid; }
        sh[1] = lo2;
    }
    __syncthreads();
    int lo = sh[0], hi = sh[1];
    int sub = t >> 7, dim = t & 127;
    float sum = 0.f;
    for (int i = lo + sub; i < hi; i += 4) sum += x[(size_t)i * 128 + dim];
    red[t] = sum;
    __syncthreads();
    if (t < 128) {
        float s = red[t] + red[t + 128] + red[t + 256] + red[t + 384];
        int cnt = hi - lo;
        out[g * 128 + t] = s * (cnt > 0 ? 1.f / (float)cnt : 1.f);
    }
}

extern "C" void kernel_launch(void* const* d_in, const int* in_sizes, int n_in,
                              void* d_out, int out_size, void* d_ws, size_t ws_size,
                              hipStream_t stream) {
    const int*   node_ids   = (const int*)d_in[0];
    const int*   edge_index = (const int*)d_in[1];   // [2][800000]
    const int*   batch      = (const int*)d_in[2];
    const float* emb        = (const float*)d_in[3];
    const float* W[3]  = {(const float*)d_in[4],  (const float*)d_in[8],  (const float*)d_in[12]};
    const float* As[3] = {(const float*)d_in[5],  (const float*)d_in[9],  (const float*)d_in[13]};
    const float* Ad[3] = {(const float*)d_in[6],  (const float*)d_in[10], (const float*)d_in[14]};
    const float* Bs[3] = {(const float*)d_in[7],  (const float*)d_in[11], (const float*)d_in[15]};

    char* ws = (char*)d_ws;
    size_t off = 0;
    auto alloc = [&](size_t bytes) {
        void* p = ws + off; off += (bytes + 255) & ~(size_t)255; return p;
    };
    float* xA      = (float*)alloc((size_t)N_NODES * 128 * 4);  // current x
    float* xB      = (float*)alloc((size_t)N_NODES * 128 * 4);  // h
    float* as_     = (float*)alloc((size_t)N_NODES * 4);
    float* ad_     = (float*)alloc((size_t)N_NODES * 4);
    int*   counts  = (int*)alloc((size_t)N_NODES * 4);          // contiguous with fill:
    int*   fill    = (int*)alloc((size_t)N_NODES * 4);          // one memset covers both
    int*   row_ptr = (int*)alloc((size_t)(N_NODES + 1) * 4);
    int*   blksum  = (int*)alloc(256 * 4);
    int*   srcs    = (int*)alloc((size_t)N_EDGES * 4);
    (void)ws_size; (void)in_sizes; (void)n_in; (void)out_size;

    // zero counts+fill in one memset (they are adjacent, incl. 256B alloc pad)
    hipMemsetAsync(counts, 0, (size_t)((char*)row_ptr - (char*)counts), stream);

    // CSR by dst (shared by all 3 layers)
    int ebl = (N_EDGES + 255) / 256;
    int nb  = (N_NODES + 255) / 256;   // 196
    k_hist   <<<ebl, 256, 0, stream>>>(edge_index, counts);
    k_scan1  <<<nb, 256, 0, stream>>>(counts, row_ptr, blksum);
    k_scan2  <<<1, 256, 0, stream>>>(blksum, row_ptr, nb);
    k_scan3  <<<nb, 256, 0, stream>>>(row_ptr, blksum);
    k_scatter<<<ebl, 256, 0, stream>>>(edge_index, row_ptr, fill, srcs);

    int gemm_blocks = (N_NODES + 127) / 128;   // 391
    for (int l = 0; l < 3; l++) {
        // layer 1 reads x through node_ids directly from emb (fused gather)
        k_gemm<<<gemm_blocks, 256, 0, stream>>>(
                 (l == 0) ? emb : xA, (l == 0) ? node_ids : nullptr,
                 W[l], As[l], Ad[l], xB, as_, ad_);
        k_aggregate<<<(N_NODES * 16 + 255) / 256, 256, 0, stream>>>((const float4*)xB,
                 as_, ad_, row_ptr, srcs, (const float4*)Bs[l], (float4*)xA,
                 (l < 2) ? 1 : 0);
    }
    k_pool<<<N_GRAPHS, 512, 0, stream>>>(xA, batch, (float*)d_out);
}

// Round 6
// 394.588 us; speedup vs baseline: 1.2674x; 1.2054x over previous
//
#include <hip/hip_runtime.h>
#include <hip/hip_fp16.h>
#include <math.h>

#define N_NODES    50000
#define N_EDGES_IN 800000
#define N_EDGES    850000   // + self loops
#define N_GRAPHS   512
#define NEG_SLOPE  0.2f
#define EPS_F      1e-16f

// ---------------- GEMM: h[N,128] = x[N,128] @ W[128,128] + fused scores -----
// 128x128 tile, 256 threads, 8x8 micro-tile. Thread (tr,tc), tr=t>>4, tc=t&15:
// rows {row0 + half*64 + tr*4 + i}, cols {half*64 + tc*4 + j}.
// Xs transposed ([k][row]) so per-k row reads are contiguous b128.
// Optional ids: X row r is read from xsrc[ids[r]] (fuses embedding gather).
// h is stored as fp16 (gather table for k_aggregate); scores stay fp32.
__global__ __launch_bounds__(256) void k_gemm(const float* __restrict__ xsrc,
                                              const int* __restrict__ ids,
                                              const float* __restrict__ W,
                                              const float* __restrict__ a_s,
                                              const float* __restrict__ a_d,
                                              __half* __restrict__ hH,
                                              float* __restrict__ as_,
                                              float* __restrict__ ad_) {
    __shared__ float Xs[32][132];   // [k][row], pad 132
    __shared__ float Ws[32][128];   // [k][col]
    int t = threadIdx.x;
    int tr = t >> 4, tc = t & 15;
    int row0 = blockIdx.x * 128;
    float acc[8][8] = {};
    for (int kc = 0; kc < 4; kc++) {
        // stage X: 128 rows x 32 k = 1024 float4, 4/thread; transpose into Xs
        #pragma unroll
        for (int i = 0; i < 4; i++) {
            int q = t + i * 256;
            int r = q >> 3, cf = q & 7;
            int gr = row0 + r; if (gr >= N_NODES) gr = N_NODES - 1;
            int srow = ids ? ids[gr] : gr;
            float4 v = ((const float4*)(xsrc + (size_t)srow * 128 + kc * 32))[cf];
            Xs[cf * 4 + 0][r] = v.x;
            Xs[cf * 4 + 1][r] = v.y;
            Xs[cf * 4 + 2][r] = v.z;
            Xs[cf * 4 + 3][r] = v.w;
        }
        // stage W: 32 k x 128 cols = 1024 float4, 4/thread, linear
        #pragma unroll
        for (int i = 0; i < 4; i++) {
            int q = t + i * 256;
            int kl = q >> 5, cf = q & 31;
            ((float4*)&Ws[kl][0])[cf] =
                ((const float4*)(W + (size_t)(kc * 32 + kl) * 128))[cf];
        }
        __syncthreads();
        #pragma unroll 4
        for (int k = 0; k < 32; k++) {
            float4 xa = *(const float4*)&Xs[k][tr * 4];
            float4 xb = *(const float4*)&Xs[k][64 + tr * 4];
            float4 wa = *(const float4*)&Ws[k][tc * 4];
            float4 wb = *(const float4*)&Ws[k][64 + tc * 4];
            float xr[8] = {xa.x, xa.y, xa.z, xa.w, xb.x, xb.y, xb.z, xb.w};
            float wc[8] = {wa.x, wa.y, wa.z, wa.w, wb.x, wb.y, wb.z, wb.w};
            #pragma unroll
            for (int i2 = 0; i2 < 8; i2++)
                #pragma unroll
                for (int j2 = 0; j2 < 8; j2++)
                    acc[i2][j2] += xr[i2] * wc[j2];
        }
        __syncthreads();
    }
    // epilogue: fp16 h stores + fused fp32 scores
    float4 saa = *(const float4*)&a_s[tc * 4], sab = *(const float4*)&a_s[64 + tc * 4];
    float4 daa = *(const float4*)&a_d[tc * 4], dab = *(const float4*)&a_d[64 + tc * 4];
    float sav[8] = {saa.x, saa.y, saa.z, saa.w, sab.x, sab.y, sab.z, sab.w};
    float dav[8] = {daa.x, daa.y, daa.z, daa.w, dab.x, dab.y, dab.z, dab.w};
    #pragma unroll
    for (int ri = 0; ri < 8; ri++) {
        int row = row0 + (ri >> 2) * 64 + tr * 4 + (ri & 3);
        bool ok = row < N_NODES;
        if (ok) {
            union { __half2 h2[2]; float2 f; } p0, p1;
            p0.h2[0] = __floats2half2_rn(acc[ri][0], acc[ri][1]);
            p0.h2[1] = __floats2half2_rn(acc[ri][2], acc[ri][3]);
            p1.h2[0] = __floats2half2_rn(acc[ri][4], acc[ri][5]);
            p1.h2[1] = __floats2half2_rn(acc[ri][6], acc[ri][7]);
            *(float2*)&hH[(size_t)row * 128 + tc * 4]      = p0.f;
            *(float2*)&hH[(size_t)row * 128 + 64 + tc * 4] = p1.f;
        }
        float ps = 0.f, pd = 0.f;
        #pragma unroll
        for (int j2 = 0; j2 < 8; j2++) { ps += acc[ri][j2] * sav[j2]; pd += acc[ri][j2] * dav[j2]; }
        #pragma unroll
        for (int off = 8; off; off >>= 1) {   // reduce across the 16 tc lanes
            ps += __shfl_xor(ps, off, 64);
            pd += __shfl_xor(pd, off, 64);
        }
        if (ok && tc == 0) { as_[row] = ps; ad_[row] = pd; }
    }
}

// ---------------- CSR build by dst ----------------
__global__ void k_hist(const int* __restrict__ ei, int* __restrict__ counts) {
    int e = blockIdx.x * blockDim.x + threadIdx.x;
    if (e >= N_EDGES) return;
    int d = (e < N_EDGES_IN) ? ei[N_EDGES_IN + e] : (e - N_EDGES_IN);
    atomicAdd(&counts[d], 1);
}

__global__ void k_scan1(const int* __restrict__ counts, int* __restrict__ row_ptr,
                        int* __restrict__ blksum) {
    __shared__ int s[256];
    int t = threadIdx.x, i = blockIdx.x * 256 + t;
    int v = (i < N_NODES) ? counts[i] : 0;
    s[t] = v; __syncthreads();
    for (int off = 1; off < 256; off <<= 1) {
        int x = (t >= off) ? s[t - off] : 0;
        __syncthreads(); s[t] += x; __syncthreads();
    }
    if (i < N_NODES) row_ptr[i] = s[t] - v;           // block-local exclusive
    if (t == 255) blksum[blockIdx.x] = s[255];
}

__global__ void k_scan2(int* __restrict__ blksum, int nb) {
    __shared__ int s[256];
    int t = threadIdx.x;
    int v = (t < nb) ? blksum[t] : 0;
    s[t] = v; __syncthreads();
    for (int off = 1; off < 256; off <<= 1) {
        int x = (t >= off) ? s[t - off] : 0;
        __syncthreads(); s[t] += x; __syncthreads();
    }
    if (t < nb) blksum[t] = s[t] - v;                 // exclusive block offsets
}

// scan3 folded into consumers: absolute lo = row_ptr[d] + blksum[d>>8]
__global__ void k_scatter(const int* __restrict__ ei, const int* __restrict__ row_ptr,
                          const int* __restrict__ blksum,
                          int* __restrict__ fill, int* __restrict__ srcs) {
    int e = blockIdx.x * blockDim.x + threadIdx.x;
    if (e >= N_EDGES) return;
    int s, d;
    if (e < N_EDGES_IN) { s = ei[e]; d = ei[N_EDGES_IN + e]; }
    else                { s = e - N_EDGES_IN; d = s; }
    int pos = row_ptr[d] + blksum[d >> 8] + atomicAdd(&fill[d], 1);
    srcs[pos] = s;
}

// ---------------- softmax + weighted aggregation, 16 lanes per dst ----------
// h table is fp16: lane reads its 8 dims as ONE 16B load, accumulates fp32.
__global__ __launch_bounds__(256) void k_aggregate(
        const float4* __restrict__ h16,   // fp16 rows: 128 halfs = 16 float4-chunks
        const float* __restrict__ as_,
        const float* __restrict__ ad_, const int* __restrict__ row_ptr,
        const int* __restrict__ blksum,
        const int* __restrict__ srcs, const float4* __restrict__ bias4,
        float4* __restrict__ xout, int do_relu) {
    int d = (blockIdx.x * blockDim.x + threadIdx.x) >> 4;
    if (d >= N_NODES) return;
    int lane = threadIdx.x & 63;
    int gl   = lane & 15;          // lane within 16-group
    int base = lane & 48;          // first lane of this group within the wave
    int lo = row_ptr[d] + blksum[d >> 8];
    int hi = (d + 1 < N_NODES) ? (row_ptr[d + 1] + blksum[(d + 1) >> 8]) : N_EDGES;
    int deg = hi - lo;             // >= 1 (self-loop)
    float add = ad_[d];

    // pass A: online softmax stats, chunks of 16; cache first 4 chunks (deg<=64)
    float eC[4]; int sC[4];
    float m_l = -1e30f, s_l = 0.f;
    #pragma unroll
    for (int c = 0; c < 4; c++) {
        float e = -1e30f; int sidx = 0;
        int j = c * 16 + gl;
        if (j < deg) {
            sidx = srcs[lo + j];
            e = as_[sidx] + add;
            e = (e > 0.f) ? e : NEG_SLOPE * e;
            float nm = fmaxf(m_l, e);
            s_l = s_l * __expf(m_l - nm) + __expf(e - nm);
            m_l = nm;
        }
        eC[c] = e; sC[c] = sidx;
    }
    for (int j0 = 64; j0 < deg; j0 += 16) {   // rare (P(deg>64) ~ 0 at avg 17)
        int j = j0 + gl;
        if (j < deg) {
            int sidx = srcs[lo + j];
            float e = as_[sidx] + add;
            e = (e > 0.f) ? e : NEG_SLOPE * e;
            float nm = fmaxf(m_l, e);
            s_l = s_l * __expf(m_l - nm) + __expf(e - nm);
            m_l = nm;
        }
    }
    float m = m_l, s = s_l;
    #pragma unroll
    for (int off = 8; off; off >>= 1) {       // 16-lane reduction, 4 steps
        float om = __shfl_xor(m, off, 64);
        float os = __shfl_xor(s, off, 64);
        float nm = fmaxf(m, om);              // finite-sentinel: no inf-inf NaN
        s = s * __expf(m - nm) + os * __expf(om - nm);
        m = nm;
    }
    float inv = 1.f / (s + EPS_F);

    // pass B: accumulate alpha * h[src] into 8 dims per lane (fp16 rows)
    float4 acc0 = make_float4(0.f, 0.f, 0.f, 0.f);
    float4 acc1 = make_float4(0.f, 0.f, 0.f, 0.f);
    #pragma unroll
    for (int c = 0; c < 4; c++) {
        int j0 = c * 16;
        if (j0 >= deg) break;
        float w = __expf(eC[c] - m) * inv;    // invalid lanes: eC=-1e30 -> w=0
        int sidx = sC[c];
        int cnt = min(16, deg - j0);
        for (int jj = 0; jj < cnt; jj += 4) {
            float w0 = __shfl(w, base + jj + 0, 64); int s0 = __shfl(sidx, base + jj + 0, 64);
            float w1 = __shfl(w, base + jj + 1, 64); int s1 = __shfl(sidx, base + jj + 1, 64);
            float w2 = __shfl(w, base + jj + 2, 64); int s2 = __shfl(sidx, base + jj + 2, 64);
            float w3 = __shfl(w, base + jj + 3, 64); int s3 = __shfl(sidx, base + jj + 3, 64);
            float4 r0 = h16[(size_t)s0 * 16 + gl];
            float4 r1 = h16[(size_t)s1 * 16 + gl];
            float4 r2 = h16[(size_t)s2 * 16 + gl];
            float4 r3 = h16[(size_t)s3 * 16 + gl];
            const __half2* p;
            float2 f0, f1, f2, f3;
            p = (const __half2*)&r0;
            f0 = __half22float2(p[0]); f1 = __half22float2(p[1]);
            f2 = __half22float2(p[2]); f3 = __half22float2(p[3]);
            acc0.x += w0*f0.x; acc0.y += w0*f0.y; acc0.z += w0*f1.x; acc0.w += w0*f1.y;
            acc1.x += w0*f2.x; acc1.y += w0*f2.y; acc1.z += w0*f3.x; acc1.w += w0*f3.y;
            p = (const __half2*)&r1;
            f0 = __half22float2(p[0]); f1 = __half22float2(p[1]);
            f2 = __half22float2(p[2]); f3 = __half22float2(p[3]);
            acc0.x += w1*f0.x; acc0.y += w1*f0.y; acc0.z += w1*f1.x; acc0.w += w1*f1.y;
            acc1.x += w1*f2.x; acc1.y += w1*f2.y; acc1.z += w1*f3.x; acc1.w += w1*f3.y;
            p = (const __half2*)&r2;
            f0 = __half22float2(p[0]); f1 = __half22float2(p[1]);
            f2 = __half22float2(p[2]); f3 = __half22float2(p[3]);
            acc0.x += w2*f0.x; acc0.y += w2*f0.y; acc0.z += w2*f1.x; acc0.w += w2*f1.y;
            acc1.x += w2*f2.x; acc1.y += w2*f2.y; acc1.z += w2*f3.x; acc1.w += w2*f3.y;
            p = (const __half2*)&r3;
            f0 = __half22float2(p[0]); f1 = __half22float2(p[1]);
            f2 = __half22float2(p[2]); f3 = __half22float2(p[3]);
            acc0.x += w3*f0.x; acc0.y += w3*f0.y; acc0.z += w3*f1.x; acc0.w += w3*f1.y;
            acc1.x += w3*f2.x; acc1.y += w3*f2.y; acc1.z += w3*f3.x; acc1.w += w3*f3.y;
        }
    }
    for (int j0 = 64; j0 < deg; j0 += 16) {   // rare tail
        int j = j0 + gl;
        float w = 0.f; int sidx = 0;
        if (j < deg) {
            int si = srcs[lo + j];
            float e = as_[si] + add;
            e = (e > 0.f) ? e : NEG_SLOPE * e;
            w = __expf(e - m) * inv;
            sidx = si;
        }
        int cnt = min(16, deg - j0);
        for (int jj = 0; jj < cnt; jj++) {
            float w0 = __shfl(w, base + jj, 64); int s0 = __shfl(sidx, base + jj, 64);
            float4 r0 = h16[(size_t)s0 * 16 + gl];
            const __half2* p = (const __half2*)&r0;
            float2 f0 = __half22float2(p[0]), f1 = __half22float2(p[1]);
            float2 f2 = __half22float2(p[2]), f3 = __half22float2(p[3]);
            acc0.x += w0*f0.x; acc0.y += w0*f0.y; acc0.z += w0*f1.x; acc0.w += w0*f1.y;
            acc1.x += w0*f2.x; acc1.y += w0*f2.y; acc1.z += w0*f3.x; acc1.w += w0*f3.y;
        }
    }
    float4 b0 = bias4[gl * 2], b1 = bias4[gl * 2 + 1];
    float4 o0 = make_float4(acc0.x + b0.x, acc0.y + b0.y, acc0.z + b0.z, acc0.w + b0.w);
    float4 o1 = make_float4(acc1.x + b1.x, acc1.y + b1.y, acc1.z + b1.z, acc1.w + b1.w);
    if (do_relu) {
        o0.x = fmaxf(o0.x, 0.f); o0.y = fmaxf(o0.y, 0.f);
        o0.z = fmaxf(o0.z, 0.f); o0.w = fmaxf(o0.w, 0.f);
        o1.x = fmaxf(o1.x, 0.f); o1.y = fmaxf(o1.y, 0.f);
        o1.z = fmaxf(o1.z, 0.f); o1.w = fmaxf(o1.w, 0.f);
    }
    xout[(size_t)d * 32 + gl * 2]     = o0;
    xout[(size_t)d * 32 + gl * 2 + 1] = o1;
}

// ---------------- global mean pool (batch is sorted) ----------------
__global__ __launch_bounds__(512) void k_pool(const float* __restrict__ x,
                                              const int* __restrict__ batch,
                                              float* __restrict__ out) {
    __shared__ float red[512];
    __shared__ int sh[2];
    int g = blockIdx.x;
    int t = threadIdx.x;   // 512 = 4 rows x 128 dims
    if (t == 0) {
        int lo = 0, hi = N_NODES;
        while (lo < hi) { int mid = (lo + hi) >> 1; if (batch[mid] < g) lo = mid + 1; else hi = mid; }
        sh[0] = lo;
        int lo2 = lo, hi2 = N_NODES;
        while (lo2 < hi2) { int mid = (lo2 + hi2) >> 1; if (batch[mid] < g + 1) lo2 = mid + 1; else hi2 = mid; }
        sh[1] = lo2;
    }
    __syncthreads();
    int lo = sh[0], hi = sh[1];
    int sub = t >> 7, dim = t & 127;
    float sum = 0.f;
    for (int i = lo + sub; i < hi; i += 4) sum += x[(size_t)i * 128 + dim];
    red[t] = sum;
    __syncthreads();
    if (t < 128) {
        float s = red[t] + red[t + 128] + red[t + 256] + red[t + 384];
        int cnt = hi - lo;
        out[g * 128 + t] = s * (cnt > 0 ? 1.f / (float)cnt : 1.f);
    }
}

extern "C" void kernel_launch(void* const* d_in, const int* in_sizes, int n_in,
                              void* d_out, int out_size, void* d_ws, size_t ws_size,
                              hipStream_t stream) {
    const int*   node_ids   = (const int*)d_in[0];
    const int*   edge_index = (const int*)d_in[1];   // [2][800000]
    const int*   batch      = (const int*)d_in[2];
    const float* emb        = (const float*)d_in[3];
    const float* W[3]  = {(const float*)d_in[4],  (const float*)d_in[8],  (const float*)d_in[12]};
    const float* As[3] = {(const float*)d_in[5],  (const float*)d_in[9],  (const float*)d_in[13]};
    const float* Ad[3] = {(const float*)d_in[6],  (const float*)d_in[10], (const float*)d_in[14]};
    const float* Bs[3] = {(const float*)d_in[7],  (const float*)d_in[11], (const float*)d_in[15]};

    char* ws = (char*)d_ws;
    size_t off = 0;
    auto alloc = [&](size_t bytes) {
        void* p = ws + off; off += (bytes + 255) & ~(size_t)255; return p;
    };
    float*  xA      = (float*)alloc((size_t)N_NODES * 128 * 4);   // current x (fp32)
    __half* hH      = (__half*)alloc((size_t)N_NODES * 128 * 2);  // h gather table (fp16)
    float*  as_     = (float*)alloc((size_t)N_NODES * 4);
    float*  ad_     = (float*)alloc((size_t)N_NODES * 4);
    int*    counts  = (int*)alloc((size_t)N_NODES * 4);           // contiguous with fill:
    int*    fill    = (int*)alloc((size_t)N_NODES * 4);           // one memset covers both
    int*    row_ptr = (int*)alloc((size_t)(N_NODES + 1) * 4);
    int*    blksum  = (int*)alloc(256 * 4);
    int*    srcs    = (int*)alloc((size_t)N_EDGES * 4);
    (void)ws_size; (void)in_sizes; (void)n_in; (void)out_size;

    // zero counts+fill in one memset (adjacent, incl. 256B alloc pad)
    hipMemsetAsync(counts, 0, (size_t)((char*)row_ptr - (char*)counts), stream);

    // CSR by dst (shared by all 3 layers)
    int ebl = (N_EDGES + 255) / 256;
    int nb  = (N_NODES + 255) / 256;   // 196
    k_hist   <<<ebl, 256, 0, stream>>>(edge_index, counts);
    k_scan1  <<<nb, 256, 0, stream>>>(counts, row_ptr, blksum);
    k_scan2  <<<1, 256, 0, stream>>>(blksum, nb);
    k_scatter<<<ebl, 256, 0, stream>>>(edge_index, row_ptr, blksum, fill, srcs);

    int gemm_blocks = (N_NODES + 127) / 128;   // 391
    for (int l = 0; l < 3; l++) {
        // layer 1 reads x through node_ids directly from emb (fused gather)
        k_gemm<<<gemm_blocks, 256, 0, stream>>>(
                 (l == 0) ? emb : xA, (l == 0) ? node_ids : nullptr,
                 W[l], As[l], Ad[l], hH, as_, ad_);
        k_aggregate<<<(N_NODES * 16 + 255) / 256, 256, 0, stream>>>((const float4*)hH,
                 as_, ad_, row_ptr, blksum, srcs, (const float4*)Bs[l], (float4*)xA,
                 (l < 2) ? 1 : 0);
    }
    k_pool<<<N_GRAPHS, 512, 0, stream>>>(xA, batch, (float*)d_out);
}

// Round 7
// 351.721 us; speedup vs baseline: 1.4219x; 1.1219x over previous
//
#include <hip/hip_runtime.h>
#include <hip/hip_fp16.h>
#include <math.h>

#define N_NODES    50000
#define N_EDGES_IN 800000
#define N_EDGES    850000   // + self loops
#define N_GRAPHS   512
#define NEG_SLOPE  0.2f
#define EPS_F      1e-16f

typedef _Float16 half8 __attribute__((ext_vector_type(8)));
typedef float    f32x4 __attribute__((ext_vector_type(4)));

// ---------------- MFMA GEMM: h[N,128] = x[N,128] @ W[128,128] + fused scores
// 128x128 tile, 256 threads = 4 waves; wave w owns rows [w*32, w*32+32).
// mfma_f32_16x16x32_f16: A[m=lane&15][k=quad*8+j], B[n=lane&15][k=quad*8+j],
// C/D: col=lane&15, row=quad*4+reg  (m89/m120-verified layouts).
// W^T staged once as fp16 [n][k] (pad 136); X staged per-64-K-chunk (pad 72).
// ids != null: row r sourced from fp32 xsrc[ids[r]] (layer-0 fused emb gather).
// Outputs: hH fp16 gather table + fp32 scores as_/ad_.
__global__ __launch_bounds__(256) void k_gemm(const void* __restrict__ xsrc,
                                              const int* __restrict__ ids,
                                              const float* __restrict__ W,
                                              const float* __restrict__ a_s,
                                              const float* __restrict__ a_d,
                                              _Float16* __restrict__ hH,
                                              float* __restrict__ as_,
                                              float* __restrict__ ad_) {
    __shared__ _Float16 WT[128][136];   // [n][k], 34.8 KB, stride 272B -> 2-way free
    __shared__ _Float16 Xs[128][72];    // [row][k within chunk], 18.4 KB
    int t = threadIdx.x;
    int row0 = blockIdx.x * 128;
    int w = t >> 6, lane = t & 63;
    int n = lane & 15, quad = lane >> 4;

    // stage W^T (fp32 -> fp16, transposed)
    #pragma unroll
    for (int i = 0; i < 16; i++) {
        int q = t + i * 256;
        int k = q >> 5;
        int n4 = (q & 31) * 4;
        float4 v = *(const float4*)(W + (size_t)k * 128 + n4);
        WT[n4 + 0][k] = (_Float16)v.x;
        WT[n4 + 1][k] = (_Float16)v.y;
        WT[n4 + 2][k] = (_Float16)v.z;
        WT[n4 + 3][k] = (_Float16)v.w;
    }

    f32x4 acc[2][8] = {};
    for (int kc = 0; kc < 2; kc++) {
        if (kc) __syncthreads();          // protect Xs reuse across chunks
        if (ids == nullptr) {             // fp16 activations
            const _Float16* xH = (const _Float16*)xsrc;
            #pragma unroll
            for (int i = 0; i < 4; i++) {
                int q = t + i * 256;
                int r = q >> 3, o8 = (q & 7) * 8;
                int gr = row0 + r; if (gr >= N_NODES) gr = N_NODES - 1;
                *(half8*)&Xs[r][o8] = *(const half8*)&xH[(size_t)gr * 128 + kc * 64 + o8];
            }
        } else {                          // layer 0: fp32 emb via node_ids
            const float* xf = (const float*)xsrc;
            #pragma unroll
            for (int i = 0; i < 4; i++) {
                int q = t + i * 256;
                int r = q >> 3, o8 = (q & 7) * 8;
                int gr = row0 + r; if (gr >= N_NODES) gr = N_NODES - 1;
                const float* src = xf + (size_t)ids[gr] * 128 + kc * 64 + o8;
                float4 v0 = *(const float4*)src;
                float4 v1 = *(const float4*)(src + 4);
                half8 hv;
                hv[0] = (_Float16)v0.x; hv[1] = (_Float16)v0.y;
                hv[2] = (_Float16)v0.z; hv[3] = (_Float16)v0.w;
                hv[4] = (_Float16)v1.x; hv[5] = (_Float16)v1.y;
                hv[6] = (_Float16)v1.z; hv[7] = (_Float16)v1.w;
                *(half8*)&Xs[r][o8] = hv;
            }
        }
        __syncthreads();
        #pragma unroll
        for (int ks = 0; ks < 2; ks++) {
            int ko = ks * 32 + quad * 8;
            half8 a0 = *(const half8*)&Xs[w * 32 + n][ko];
            half8 a1 = *(const half8*)&Xs[w * 32 + 16 + n][ko];
            int kg = kc * 64 + ko;
            #pragma unroll
            for (int c = 0; c < 8; c++) {
                half8 b = *(const half8*)&WT[c * 16 + n][kg];
                acc[0][c] = __builtin_amdgcn_mfma_f32_16x16x32_f16(a0, b, acc[0][c], 0, 0, 0);
                acc[1][c] = __builtin_amdgcn_mfma_f32_16x16x32_f16(a1, b, acc[1][c], 0, 0, 0);
            }
        }
    }

    // epilogue: fp16 h stores + fused fp32 scores
    float sa[8], da[8];
    #pragma unroll
    for (int c = 0; c < 8; c++) { sa[c] = a_s[c * 16 + n]; da[c] = a_d[c * 16 + n]; }
    #pragma unroll
    for (int r = 0; r < 2; r++) {
        float ps[4] = {0.f, 0.f, 0.f, 0.f}, pd[4] = {0.f, 0.f, 0.f, 0.f};
        #pragma unroll
        for (int reg = 0; reg < 4; reg++) {
            int row = row0 + w * 32 + r * 16 + quad * 4 + reg;
            bool ok = row < N_NODES;
            #pragma unroll
            for (int c = 0; c < 8; c++) {
                float v = acc[r][c][reg];
                ps[reg] += v * sa[c];
                pd[reg] += v * da[c];
                if (ok) hH[(size_t)row * 128 + c * 16 + n] = (_Float16)v;
            }
        }
        #pragma unroll
        for (int off = 1; off < 16; off <<= 1) {   // reduce over the 16 n-lanes
            #pragma unroll
            for (int reg = 0; reg < 4; reg++) {
                ps[reg] += __shfl_xor(ps[reg], off, 64);
                pd[reg] += __shfl_xor(pd[reg], off, 64);
            }
        }
        if (n == 0) {
            #pragma unroll
            for (int reg = 0; reg < 4; reg++) {
                int row = row0 + w * 32 + r * 16 + quad * 4 + reg;
                if (row < N_NODES) { as_[row] = ps[reg]; ad_[row] = pd[reg]; }
            }
        }
    }
}

// ---------------- CSR build by dst ----------------
__global__ void k_hist(const int* __restrict__ ei, int* __restrict__ counts) {
    int e = blockIdx.x * blockDim.x + threadIdx.x;
    if (e >= N_EDGES) return;
    int d = (e < N_EDGES_IN) ? ei[N_EDGES_IN + e] : (e - N_EDGES_IN);
    atomicAdd(&counts[d], 1);
}

__global__ void k_scan1(const int* __restrict__ counts, int* __restrict__ row_ptr,
                        int* __restrict__ blksum) {
    __shared__ int s[256];
    int t = threadIdx.x, i = blockIdx.x * 256 + t;
    int v = (i < N_NODES) ? counts[i] : 0;
    s[t] = v; __syncthreads();
    for (int off = 1; off < 256; off <<= 1) {
        int x = (t >= off) ? s[t - off] : 0;
        __syncthreads(); s[t] += x; __syncthreads();
    }
    if (i < N_NODES) row_ptr[i] = s[t] - v;           // block-local exclusive
    if (t == 255) blksum[blockIdx.x] = s[255];
}

__global__ void k_scan2(int* __restrict__ blksum, int nb) {
    __shared__ int s[256];
    int t = threadIdx.x;
    int v = (t < nb) ? blksum[t] : 0;
    s[t] = v; __syncthreads();
    for (int off = 1; off < 256; off <<= 1) {
        int x = (t >= off) ? s[t - off] : 0;
        __syncthreads(); s[t] += x; __syncthreads();
    }
    if (t < nb) blksum[t] = s[t] - v;                 // exclusive block offsets
}

// scan3 folded into consumers: absolute lo = row_ptr[d] + blksum[d>>8]
__global__ void k_scatter(const int* __restrict__ ei, const int* __restrict__ row_ptr,
                          const int* __restrict__ blksum,
                          int* __restrict__ fill, int* __restrict__ srcs) {
    int e = blockIdx.x * blockDim.x + threadIdx.x;
    if (e >= N_EDGES) return;
    int s, d;
    if (e < N_EDGES_IN) { s = ei[e]; d = ei[N_EDGES_IN + e]; }
    else                { s = e - N_EDGES_IN; d = s; }
    int pos = row_ptr[d] + blksum[d >> 8] + atomicAdd(&fill[d], 1);
    srcs[pos] = s;
}

// ---------------- softmax + weighted aggregation, 16 lanes per dst ----------
// h table fp16 (one 16B load = 8 dims/lane); output xout also fp16.
__global__ __launch_bounds__(256) void k_aggregate(
        const float4* __restrict__ h16,   // fp16 rows: 128 halfs = 16 float4-chunks
        const float* __restrict__ as_,
        const float* __restrict__ ad_, const int* __restrict__ row_ptr,
        const int* __restrict__ blksum,
        const int* __restrict__ srcs, const float4* __restrict__ bias4,
        float4* __restrict__ xout16,      // fp16 rows: d*16 + gl
        int do_relu) {
    int d = (blockIdx.x * blockDim.x + threadIdx.x) >> 4;
    if (d >= N_NODES) return;
    int lane = threadIdx.x & 63;
    int gl   = lane & 15;          // lane within 16-group
    int base = lane & 48;          // first lane of this group within the wave
    int lo = row_ptr[d] + blksum[d >> 8];
    int hi = (d + 1 < N_NODES) ? (row_ptr[d + 1] + blksum[(d + 1) >> 8]) : N_EDGES;
    int deg = hi - lo;             // >= 1 (self-loop)
    float add = ad_[d];

    // pass A: online softmax stats, chunks of 16; cache first 4 chunks (deg<=64)
    float eC[4]; int sC[4];
    float m_l = -1e30f, s_l = 0.f;
    #pragma unroll
    for (int c = 0; c < 4; c++) {
        float e = -1e30f; int sidx = 0;
        int j = c * 16 + gl;
        if (j < deg) {
            sidx = srcs[lo + j];
            e = as_[sidx] + add;
            e = (e > 0.f) ? e : NEG_SLOPE * e;
            float nm = fmaxf(m_l, e);
            s_l = s_l * __expf(m_l - nm) + __expf(e - nm);
            m_l = nm;
        }
        eC[c] = e; sC[c] = sidx;
    }
    for (int j0 = 64; j0 < deg; j0 += 16) {   // rare (P(deg>64) ~ 0 at avg 17)
        int j = j0 + gl;
        if (j < deg) {
            int sidx = srcs[lo + j];
            float e = as_[sidx] + add;
            e = (e > 0.f) ? e : NEG_SLOPE * e;
            float nm = fmaxf(m_l, e);
            s_l = s_l * __expf(m_l - nm) + __expf(e - nm);
            m_l = nm;
        }
    }
    float m = m_l, s = s_l;
    #pragma unroll
    for (int off = 8; off; off >>= 1) {       // 16-lane reduction, 4 steps
        float om = __shfl_xor(m, off, 64);
        float os = __shfl_xor(s, off, 64);
        float nm = fmaxf(m, om);              // finite-sentinel: no inf-inf NaN
        s = s * __expf(m - nm) + os * __expf(om - nm);
        m = nm;
    }
    float inv = 1.f / (s + EPS_F);

    // pass B: accumulate alpha * h[src] into 8 dims per lane (fp16 rows)
    float4 acc0 = make_float4(0.f, 0.f, 0.f, 0.f);
    float4 acc1 = make_float4(0.f, 0.f, 0.f, 0.f);
    #pragma unroll
    for (int c = 0; c < 4; c++) {
        int j0 = c * 16;
        if (j0 >= deg) break;
        float w = __expf(eC[c] - m) * inv;    // invalid lanes: eC=-1e30 -> w=0
        int sidx = sC[c];
        int cnt = min(16, deg - j0);
        for (int jj = 0; jj < cnt; jj += 4) {
            float w0 = __shfl(w, base + jj + 0, 64); int s0 = __shfl(sidx, base + jj + 0, 64);
            float w1 = __shfl(w, base + jj + 1, 64); int s1 = __shfl(sidx, base + jj + 1, 64);
            float w2 = __shfl(w, base + jj + 2, 64); int s2 = __shfl(sidx, base + jj + 2, 64);
            float w3 = __shfl(w, base + jj + 3, 64); int s3 = __shfl(sidx, base + jj + 3, 64);
            float4 r0 = h16[(size_t)s0 * 16 + gl];
            float4 r1 = h16[(size_t)s1 * 16 + gl];
            float4 r2 = h16[(size_t)s2 * 16 + gl];
            float4 r3 = h16[(size_t)s3 * 16 + gl];
            const __half2* p;
            float2 f0, f1, f2, f3;
            p = (const __half2*)&r0;
            f0 = __half22float2(p[0]); f1 = __half22float2(p[1]);
            f2 = __half22float2(p[2]); f3 = __half22float2(p[3]);
            acc0.x += w0*f0.x; acc0.y += w0*f0.y; acc0.z += w0*f1.x; acc0.w += w0*f1.y;
            acc1.x += w0*f2.x; acc1.y += w0*f2.y; acc1.z += w0*f3.x; acc1.w += w0*f3.y;
            p = (const __half2*)&r1;
            f0 = __half22float2(p[0]); f1 = __half22float2(p[1]);
            f2 = __half22float2(p[2]); f3 = __half22float2(p[3]);
            acc0.x += w1*f0.x; acc0.y += w1*f0.y; acc0.z += w1*f1.x; acc0.w += w1*f1.y;
            acc1.x += w1*f2.x; acc1.y += w1*f2.y; acc1.z += w1*f3.x; acc1.w += w1*f3.y;
            p = (const __half2*)&r2;
            f0 = __half22float2(p[0]); f1 = __half22float2(p[1]);
            f2 = __half22float2(p[2]); f3 = __half22float2(p[3]);
            acc0.x += w2*f0.x; acc0.y += w2*f0.y; acc0.z += w2*f1.x; acc0.w += w2*f1.y;
            acc1.x += w2*f2.x; acc1.y += w2*f2.y; acc1.z += w2*f3.x; acc1.w += w2*f3.y;
            p = (const __half2*)&r3;
            f0 = __half22float2(p[0]); f1 = __half22float2(p[1]);
            f2 = __half22float2(p[2]); f3 = __half22float2(p[3]);
            acc0.x += w3*f0.x; acc0.y += w3*f0.y; acc0.z += w3*f1.x; acc0.w += w3*f1.y;
            acc1.x += w3*f2.x; acc1.y += w3*f2.y; acc1.z += w3*f3.x; acc1.w += w3*f3.y;
        }
    }
    for (int j0 = 64; j0 < deg; j0 += 16) {   // rare tail
        int j = j0 + gl;
        float w = 0.f; int sidx = 0;
        if (j < deg) {
            int si = srcs[lo + j];
            float e = as_[si] + add;
            e = (e > 0.f) ? e : NEG_SLOPE * e;
            w = __expf(e - m) * inv;
            sidx = si;
        }
        int cnt = min(16, deg - j0);
        for (int jj = 0; jj < cnt; jj++) {
            float w0 = __shfl(w, base + jj, 64); int s0 = __shfl(sidx, base + jj, 64);
            float4 r0 = h16[(size_t)s0 * 16 + gl];
            const __half2* p = (const __half2*)&r0;
            float2 f0 = __half22float2(p[0]), f1 = __half22float2(p[1]);
            float2 f2 = __half22float2(p[2]), f3 = __half22float2(p[3]);
            acc0.x += w0*f0.x; acc0.y += w0*f0.y; acc0.z += w0*f1.x; acc0.w += w0*f1.y;
            acc1.x += w0*f2.x; acc1.y += w0*f2.y; acc1.z += w0*f3.x; acc1.w += w0*f3.y;
        }
    }
    float4 b0 = bias4[gl * 2], b1 = bias4[gl * 2 + 1];
    float4 o0 = make_float4(acc0.x + b0.x, acc0.y + b0.y, acc0.z + b0.z, acc0.w + b0.w);
    float4 o1 = make_float4(acc1.x + b1.x, acc1.y + b1.y, acc1.z + b1.z, acc1.w + b1.w);
    if (do_relu) {
        o0.x = fmaxf(o0.x, 0.f); o0.y = fmaxf(o0.y, 0.f);
        o0.z = fmaxf(o0.z, 0.f); o0.w = fmaxf(o0.w, 0.f);
        o1.x = fmaxf(o1.x, 0.f); o1.y = fmaxf(o1.y, 0.f);
        o1.z = fmaxf(o1.z, 0.f); o1.w = fmaxf(o1.w, 0.f);
    }
    union { __half2 h2[4]; float4 f; } pk;
    pk.h2[0] = __floats2half2_rn(o0.x, o0.y);
    pk.h2[1] = __floats2half2_rn(o0.z, o0.w);
    pk.h2[2] = __floats2half2_rn(o1.x, o1.y);
    pk.h2[3] = __floats2half2_rn(o1.z, o1.w);
    xout16[(size_t)d * 16 + gl] = pk.f;
}

// ---------------- global mean pool over fp16 x (batch is sorted) ------------
__global__ __launch_bounds__(512) void k_pool(const __half* __restrict__ x,
                                              const int* __restrict__ batch,
                                              float* __restrict__ out) {
    __shared__ float red[512];
    __shared__ int sh[2];
    int g = blockIdx.x;
    int t = threadIdx.x;   // 512 = 4 rows x 128 dims
    if (t == 0) {
        int lo = 0, hi = N_NODES;
        while (lo < hi) { int mid = (lo + hi) >> 1; if (batch[mid] < g) lo = mid + 1; else hi = mid; }
        sh[0] = lo;
        int lo2 = lo, hi2 = N_NODES;
        while (lo2 < hi2) { int mid = (lo2 + hi2) >> 1; if (batch[mid] < g + 1) lo2 = mid + 1; else hi2 = mid; }
        sh[1] = lo2;
    }
    __syncthreads();
    int lo = sh[0], hi = sh[1];
    int sub = t >> 7, dim = t & 127;
    float sum = 0.f;
    for (int i = lo + sub; i < hi; i += 4) sum += __half2float(x[(size_t)i * 128 + dim]);
    red[t] = sum;
    __syncthreads();
    if (t < 128) {
        float s = red[t] + red[t + 128] + red[t + 256] + red[t + 384];
        int cnt = hi - lo;
        out[g * 128 + t] = s * (cnt > 0 ? 1.f / (float)cnt : 1.f);
    }
}

extern "C" void kernel_launch(void* const* d_in, const int* in_sizes, int n_in,
                              void* d_out, int out_size, void* d_ws, size_t ws_size,
                              hipStream_t stream) {
    const int*   node_ids   = (const int*)d_in[0];
    const int*   edge_index = (const int*)d_in[1];   // [2][800000]
    const int*   batch      = (const int*)d_in[2];
    const float* emb        = (const float*)d_in[3];
    const float* W[3]  = {(const float*)d_in[4],  (const float*)d_in[8],  (const float*)d_in[12]};
    const float* As[3] = {(const float*)d_in[5],  (const float*)d_in[9],  (const float*)d_in[13]};
    const float* Ad[3] = {(const float*)d_in[6],  (const float*)d_in[10], (const float*)d_in[14]};
    const float* Bs[3] = {(const float*)d_in[7],  (const float*)d_in[11], (const float*)d_in[15]};

    char* ws = (char*)d_ws;
    size_t off = 0;
    auto alloc = [&](size_t bytes) {
        void* p = ws + off; off += (bytes + 255) & ~(size_t)255; return p;
    };
    _Float16* xH     = (_Float16*)alloc((size_t)N_NODES * 128 * 2);  // activations (fp16)
    _Float16* hH     = (_Float16*)alloc((size_t)N_NODES * 128 * 2);  // h gather table (fp16)
    float*  as_     = (float*)alloc((size_t)N_NODES * 4);
    float*  ad_     = (float*)alloc((size_t)N_NODES * 4);
    int*    counts  = (int*)alloc((size_t)N_NODES * 4);              // contiguous with fill:
    int*    fill    = (int*)alloc((size_t)N_NODES * 4);              // one memset covers both
    int*    row_ptr = (int*)alloc((size_t)(N_NODES + 1) * 4);
    int*    blksum  = (int*)alloc(256 * 4);
    int*    srcs    = (int*)alloc((size_t)N_EDGES * 4);
    (void)ws_size; (void)in_sizes; (void)n_in; (void)out_size;

    // zero counts+fill in one memset (adjacent, incl. 256B alloc pad)
    hipMemsetAsync(counts, 0, (size_t)((char*)row_ptr - (char*)counts), stream);

    // CSR by dst (shared by all 3 layers)
    int ebl = (N_EDGES + 255) / 256;
    int nb  = (N_NODES + 255) / 256;   // 196
    k_hist   <<<ebl, 256, 0, stream>>>(edge_index, counts);
    k_scan1  <<<nb, 256, 0, stream>>>(counts, row_ptr, blksum);
    k_scan2  <<<1, 256, 0, stream>>>(blksum, nb);
    k_scatter<<<ebl, 256, 0, stream>>>(edge_index, row_ptr, blksum, fill, srcs);

    int gemm_blocks = (N_NODES + 127) / 128;   // 391
    for (int l = 0; l < 3; l++) {
        // layer 0 reads fp32 emb through node_ids (fused gather); others read fp16 xH
        k_gemm<<<gemm_blocks, 256, 0, stream>>>(
                 (l == 0) ? (const void*)emb : (const void*)xH,
                 (l == 0) ? node_ids : nullptr,
                 W[l], As[l], Ad[l], hH, as_, ad_);
        k_aggregate<<<(N_NODES * 16 + 255) / 256, 256, 0, stream>>>((const float4*)hH,
                 as_, ad_, row_ptr, blksum, srcs, (const float4*)Bs[l], (float4*)xH,
                 (l < 2) ? 1 : 0);
    }
    k_pool<<<N_GRAPHS, 512, 0, stream>>>((const __half*)xH, batch, (float*)d_out);
}

// Round 8
// 305.429 us; speedup vs baseline: 1.6374x; 1.1516x over previous
//
#include <hip/hip_runtime.h>
#include <hip/hip_fp16.h>
#include <math.h>

#define N_NODES    50000
#define N_EDGES_IN 800000
#define N_EDGES    850000   // + self loops
#define N_GRAPHS   512
#define NEG_SLOPE  0.2f
#define EPS_F      1e-16f

#define NB_COARSE  196              // ceil(50000/256) coarse dst buckets
#define NSUB       8                // sub-cursors per bucket (contention spread)
#define NBINS      (NB_COARSE*NSUB) // 1568

typedef _Float16 half8 __attribute__((ext_vector_type(8)));
typedef float    f32x4 __attribute__((ext_vector_type(4)));

// ---------------- MFMA GEMM: h[N,128] = x[N,128] @ W[128,128] + fused scores
// (R7 structure, verified)
__global__ __launch_bounds__(256) void k_gemm(const void* __restrict__ xsrc,
                                              const int* __restrict__ ids,
                                              const float* __restrict__ W,
                                              const float* __restrict__ a_s,
                                              const float* __restrict__ a_d,
                                              _Float16* __restrict__ hH,
                                              float* __restrict__ as_,
                                              float* __restrict__ ad_) {
    __shared__ _Float16 WT[128][136];   // [n][k]
    __shared__ _Float16 Xs[128][72];    // [row][k within chunk]
    int t = threadIdx.x;
    int row0 = blockIdx.x * 128;
    int w = t >> 6, lane = t & 63;
    int n = lane & 15, quad = lane >> 4;

    #pragma unroll
    for (int i = 0; i < 16; i++) {
        int q = t + i * 256;
        int k = q >> 5;
        int n4 = (q & 31) * 4;
        float4 v = *(const float4*)(W + (size_t)k * 128 + n4);
        WT[n4 + 0][k] = (_Float16)v.x;
        WT[n4 + 1][k] = (_Float16)v.y;
        WT[n4 + 2][k] = (_Float16)v.z;
        WT[n4 + 3][k] = (_Float16)v.w;
    }

    f32x4 acc[2][8] = {};
    for (int kc = 0; kc < 2; kc++) {
        if (kc) __syncthreads();
        if (ids == nullptr) {
            const _Float16* xH = (const _Float16*)xsrc;
            #pragma unroll
            for (int i = 0; i < 4; i++) {
                int q = t + i * 256;
                int r = q >> 3, o8 = (q & 7) * 8;
                int gr = row0 + r; if (gr >= N_NODES) gr = N_NODES - 1;
                *(half8*)&Xs[r][o8] = *(const half8*)&xH[(size_t)gr * 128 + kc * 64 + o8];
            }
        } else {
            const float* xf = (const float*)xsrc;
            #pragma unroll
            for (int i = 0; i < 4; i++) {
                int q = t + i * 256;
                int r = q >> 3, o8 = (q & 7) * 8;
                int gr = row0 + r; if (gr >= N_NODES) gr = N_NODES - 1;
                const float* src = xf + (size_t)ids[gr] * 128 + kc * 64 + o8;
                float4 v0 = *(const float4*)src;
                float4 v1 = *(const float4*)(src + 4);
                half8 hv;
                hv[0] = (_Float16)v0.x; hv[1] = (_Float16)v0.y;
                hv[2] = (_Float16)v0.z; hv[3] = (_Float16)v0.w;
                hv[4] = (_Float16)v1.x; hv[5] = (_Float16)v1.y;
                hv[6] = (_Float16)v1.z; hv[7] = (_Float16)v1.w;
                *(half8*)&Xs[r][o8] = hv;
            }
        }
        __syncthreads();
        #pragma unroll
        for (int ks = 0; ks < 2; ks++) {
            int ko = ks * 32 + quad * 8;
            half8 a0 = *(const half8*)&Xs[w * 32 + n][ko];
            half8 a1 = *(const half8*)&Xs[w * 32 + 16 + n][ko];
            int kg = kc * 64 + ko;
            #pragma unroll
            for (int c = 0; c < 8; c++) {
                half8 b = *(const half8*)&WT[c * 16 + n][kg];
                acc[0][c] = __builtin_amdgcn_mfma_f32_16x16x32_f16(a0, b, acc[0][c], 0, 0, 0);
                acc[1][c] = __builtin_amdgcn_mfma_f32_16x16x32_f16(a1, b, acc[1][c], 0, 0, 0);
            }
        }
    }

    float sa[8], da[8];
    #pragma unroll
    for (int c = 0; c < 8; c++) { sa[c] = a_s[c * 16 + n]; da[c] = a_d[c * 16 + n]; }
    #pragma unroll
    for (int r = 0; r < 2; r++) {
        float ps[4] = {0.f, 0.f, 0.f, 0.f}, pd[4] = {0.f, 0.f, 0.f, 0.f};
        #pragma unroll
        for (int reg = 0; reg < 4; reg++) {
            int row = row0 + w * 32 + r * 16 + quad * 4 + reg;
            bool ok = row < N_NODES;
            #pragma unroll
            for (int c = 0; c < 8; c++) {
                float v = acc[r][c][reg];
                ps[reg] += v * sa[c];
                pd[reg] += v * da[c];
                if (ok) hH[(size_t)row * 128 + c * 16 + n] = (_Float16)v;
            }
        }
        #pragma unroll
        for (int off = 1; off < 16; off <<= 1) {
            #pragma unroll
            for (int reg = 0; reg < 4; reg++) {
                ps[reg] += __shfl_xor(ps[reg], off, 64);
                pd[reg] += __shfl_xor(pd[reg], off, 64);
            }
        }
        if (n == 0) {
            #pragma unroll
            for (int reg = 0; reg < 4; reg++) {
                int row = row0 + w * 32 + r * 16 + quad * 4 + reg;
                if (row < N_NODES) { as_[row] = ps[reg]; ad_[row] = pd[reg]; }
            }
        }
    }
}

// ---------------- multisplit CSR build ----------------
// bin key = (dst>>8)*8 + sub, sub = (e>>10)&7  (sub == scat1 blockIdx & 7)
__global__ __launch_bounds__(256) void k_chist(const int* __restrict__ ei,
                                               int* __restrict__ gbins) {
    __shared__ int lh[NBINS];
    for (int i = threadIdx.x; i < NBINS; i += 256) lh[i] = 0;
    __syncthreads();
    for (int e = blockIdx.x * 256 + threadIdx.x; e < N_EDGES; e += gridDim.x * 256) {
        int d = (e < N_EDGES_IN) ? ei[N_EDGES_IN + e] : (e - N_EDGES_IN);
        atomicAdd(&lh[(d >> 8) * NSUB + ((e >> 10) & 7)], 1);
    }
    __syncthreads();
    for (int i = threadIdx.x; i < NBINS; i += 256) {
        int v = lh[i];
        if (v) atomicAdd(&gbins[i], v);
    }
}

// exclusive scan of gbins[NBINS] -> cbase[NBINS+1]; also row_ptr[N_NODES]=N_EDGES
__global__ __launch_bounds__(256) void k_cscan(const int* __restrict__ gbins,
                                               int* __restrict__ cbase,
                                               int* __restrict__ row_ptr) {
    __shared__ int part[256];
    int t = threadIdx.x;
    int base = t * 7;                     // 256*7 = 1792 >= 1568
    int lv[7];
    int sum = 0;
    #pragma unroll
    for (int i = 0; i < 7; i++) {
        int idx = base + i;
        int v = (idx < NBINS) ? gbins[idx] : 0;
        lv[i] = sum; sum += v;
    }
    part[t] = sum; __syncthreads();
    for (int off = 1; off < 256; off <<= 1) {
        int x = (t >= off) ? part[t - off] : 0;
        __syncthreads(); part[t] += x; __syncthreads();
    }
    int excl = part[t] - sum;
    #pragma unroll
    for (int i = 0; i < 7; i++) {
        int idx = base + i;
        if (idx < NBINS) cbase[idx] = excl + lv[i];
    }
    if (t == 0) { cbase[NBINS] = N_EDGES; row_ptr[N_NODES] = N_EDGES; }
}

// pass 1: 1024 edges/block; per-(block,bucket) runs written contiguously
__global__ __launch_bounds__(256) void k_scat1(const int* __restrict__ ei,
                                               const int* __restrict__ cbase,
                                               int* __restrict__ gcur,
                                               int* __restrict__ recs) {
    __shared__ int lcnt[NB_COARSE];
    __shared__ int lbase[NB_COARSE];
    int t = threadIdx.x;
    int e0 = blockIdx.x * 1024;
    int sub = blockIdx.x & 7;            // == (e>>10)&7 for all e in this block
    for (int i = t; i < NB_COARSE; i += 256) lcnt[i] = 0;
    __syncthreads();
    int s[4], d[4], b[4], r[4];
    #pragma unroll
    for (int i = 0; i < 4; i++) {
        int e = e0 + t + i * 256;
        if (e < N_EDGES) {
            if (e < N_EDGES_IN) { s[i] = ei[e]; d[i] = ei[N_EDGES_IN + e]; }
            else                { s[i] = e - N_EDGES_IN; d[i] = s[i]; }
            b[i] = d[i] >> 8;
            r[i] = atomicAdd(&lcnt[b[i]], 1);
        } else b[i] = -1;
    }
    __syncthreads();
    for (int i = t; i < NB_COARSE; i += 256) {
        int c = lcnt[i];
        lbase[i] = c ? (cbase[i * NSUB + sub] + atomicAdd(&gcur[i * NSUB + sub], c)) : 0;
    }
    __syncthreads();
    #pragma unroll
    for (int i = 0; i < 4; i++)
        if (b[i] >= 0) recs[lbase[b[i]] + r[i]] = s[i] | ((d[i] & 255) << 16);
}

// pass 2: one block per coarse bucket; fine hist+scan in LDS; all writes land
// in the block's own contiguous region -> full-line writebacks.
__global__ __launch_bounds__(256) void k_scat2(const int* __restrict__ recs,
                                               const int* __restrict__ cbase,
                                               int* __restrict__ row_ptr,
                                               int* __restrict__ srcs) {
    __shared__ int hist[256];
    __shared__ int off[256];
    __shared__ int rank[256];
    int b = blockIdx.x;
    int t = threadIdx.x;
    int lo = cbase[b * NSUB];
    int hi = cbase[(b + 1) * NSUB];
    int cnt = hi - lo;
    hist[t] = 0; rank[t] = 0;
    __syncthreads();
    for (int i = t; i < cnt; i += 256) atomicAdd(&hist[recs[lo + i] >> 16], 1);
    __syncthreads();
    int v = hist[t];
    off[t] = v; __syncthreads();
    for (int o = 1; o < 256; o <<= 1) {
        int x = (t >= o) ? off[t - o] : 0;
        __syncthreads(); off[t] += x; __syncthreads();
    }
    int excl = off[t] - v;
    int dglob = b * 256 + t;
    if (dglob < N_NODES) row_ptr[dglob] = lo + excl;
    __syncthreads();
    off[t] = excl;
    __syncthreads();
    for (int i = t; i < cnt; i += 256) {
        int rec = recs[lo + i];
        int dl = rec >> 16;
        int rk = atomicAdd(&rank[dl], 1);
        srcs[lo + off[dl] + rk] = rec & 0xFFFF;
    }
}

// ---------------- softmax + weighted aggregation, 16 lanes per dst ----------
__global__ __launch_bounds__(256) void k_aggregate(
        const float4* __restrict__ h16,
        const float* __restrict__ as_,
        const float* __restrict__ ad_, const int* __restrict__ row_ptr,
        const int* __restrict__ srcs, const float4* __restrict__ bias4,
        float4* __restrict__ xout16, int do_relu) {
    int d = (blockIdx.x * blockDim.x + threadIdx.x) >> 4;
    if (d >= N_NODES) return;
    int lane = threadIdx.x & 63;
    int gl   = lane & 15;
    int base = lane & 48;
    int lo = row_ptr[d], hi = row_ptr[d + 1];
    int deg = hi - lo;             // >= 1 (self-loop)
    float add = ad_[d];

    float eC[4]; int sC[4];
    float m_l = -1e30f, s_l = 0.f;
    #pragma unroll
    for (int c = 0; c < 4; c++) {
        float e = -1e30f; int sidx = 0;
        int j = c * 16 + gl;
        if (j < deg) {
            sidx = srcs[lo + j];
            e = as_[sidx] + add;
            e = (e > 0.f) ? e : NEG_SLOPE * e;
            float nm = fmaxf(m_l, e);
            s_l = s_l * __expf(m_l - nm) + __expf(e - nm);
            m_l = nm;
        }
        eC[c] = e; sC[c] = sidx;
    }
    for (int j0 = 64; j0 < deg; j0 += 16) {
        int j = j0 + gl;
        if (j < deg) {
            int sidx = srcs[lo + j];
            float e = as_[sidx] + add;
            e = (e > 0.f) ? e : NEG_SLOPE * e;
            float nm = fmaxf(m_l, e);
            s_l = s_l * __expf(m_l - nm) + __expf(e - nm);
            m_l = nm;
        }
    }
    float m = m_l, s = s_l;
    #pragma unroll
    for (int off = 8; off; off >>= 1) {
        float om = __shfl_xor(m, off, 64);
        float os = __shfl_xor(s, off, 64);
        float nm = fmaxf(m, om);
        s = s * __expf(m - nm) + os * __expf(om - nm);
        m = nm;
    }
    float inv = 1.f / (s + EPS_F);

    float4 acc0 = make_float4(0.f, 0.f, 0.f, 0.f);
    float4 acc1 = make_float4(0.f, 0.f, 0.f, 0.f);
    #pragma unroll
    for (int c = 0; c < 4; c++) {
        int j0 = c * 16;
        if (j0 >= deg) break;
        float w = __expf(eC[c] - m) * inv;
        int sidx = sC[c];
        int cnt = min(16, deg - j0);
        for (int jj = 0; jj < cnt; jj += 4) {
            float w0 = __shfl(w, base + jj + 0, 64); int s0 = __shfl(sidx, base + jj + 0, 64);
            float w1 = __shfl(w, base + jj + 1, 64); int s1 = __shfl(sidx, base + jj + 1, 64);
            float w2 = __shfl(w, base + jj + 2, 64); int s2 = __shfl(sidx, base + jj + 2, 64);
            float w3 = __shfl(w, base + jj + 3, 64); int s3 = __shfl(sidx, base + jj + 3, 64);
            float4 r0 = h16[(size_t)s0 * 16 + gl];
            float4 r1 = h16[(size_t)s1 * 16 + gl];
            float4 r2 = h16[(size_t)s2 * 16 + gl];
            float4 r3 = h16[(size_t)s3 * 16 + gl];
            const __half2* p;
            float2 f0, f1, f2, f3;
            p = (const __half2*)&r0;
            f0 = __half22float2(p[0]); f1 = __half22float2(p[1]);
            f2 = __half22float2(p[2]); f3 = __half22float2(p[3]);
            acc0.x += w0*f0.x; acc0.y += w0*f0.y; acc0.z += w0*f1.x; acc0.w += w0*f1.y;
            acc1.x += w0*f2.x; acc1.y += w0*f2.y; acc1.z += w0*f3.x; acc1.w += w0*f3.y;
            p = (const __half2*)&r1;
            f0 = __half22float2(p[0]); f1 = __half22float2(p[1]);
            f2 = __half22float2(p[2]); f3 = __half22float2(p[3]);
            acc0.x += w1*f0.x; acc0.y += w1*f0.y; acc0.z += w1*f1.x; acc0.w += w1*f1.y;
            acc1.x += w1*f2.x; acc1.y += w1*f2.y; acc1.z += w1*f3.x; acc1.w += w1*f3.y;
            p = (const __half2*)&r2;
            f0 = __half22float2(p[0]); f1 = __half22float2(p[1]);
            f2 = __half22float2(p[2]); f3 = __half22float2(p[3]);
            acc0.x += w2*f0.x; acc0.y += w2*f0.y; acc0.z += w2*f1.x; acc0.w += w2*f1.y;
            acc1.x += w2*f2.x; acc1.y += w2*f2.y; acc1.z += w2*f3.x; acc1.w += w2*f3.y;
            p = (const __half2*)&r3;
            f0 = __half22float2(p[0]); f1 = __half22float2(p[1]);
            f2 = __half22float2(p[2]); f3 = __half22float2(p[3]);
            acc0.x += w3*f0.x; acc0.y += w3*f0.y; acc0.z += w3*f1.x; acc0.w += w3*f1.y;
            acc1.x += w3*f2.x; acc1.y += w3*f2.y; acc1.z += w3*f3.x; acc1.w += w3*f3.y;
        }
    }
    for (int j0 = 64; j0 < deg; j0 += 16) {
        int j = j0 + gl;
        float w = 0.f; int sidx = 0;
        if (j < deg) {
            int si = srcs[lo + j];
            float e = as_[si] + add;
            e = (e > 0.f) ? e : NEG_SLOPE * e;
            w = __expf(e - m) * inv;
            sidx = si;
        }
        int cnt = min(16, deg - j0);
        for (int jj = 0; jj < cnt; jj++) {
            float w0 = __shfl(w, base + jj, 64); int s0 = __shfl(sidx, base + jj, 64);
            float4 r0 = h16[(size_t)s0 * 16 + gl];
            const __half2* p = (const __half2*)&r0;
            float2 f0 = __half22float2(p[0]), f1 = __half22float2(p[1]);
            float2 f2 = __half22float2(p[2]), f3 = __half22float2(p[3]);
            acc0.x += w0*f0.x; acc0.y += w0*f0.y; acc0.z += w0*f1.x; acc0.w += w0*f1.y;
            acc1.x += w0*f2.x; acc1.y += w0*f2.y; acc1.z += w0*f3.x; acc1.w += w0*f3.y;
        }
    }
    float4 b0 = bias4[gl * 2], b1 = bias4[gl * 2 + 1];
    float4 o0 = make_float4(acc0.x + b0.x, acc0.y + b0.y, acc0.z + b0.z, acc0.w + b0.w);
    float4 o1 = make_float4(acc1.x + b1.x, acc1.y + b1.y, acc1.z + b1.z, acc1.w + b1.w);
    if (do_relu) {
        o0.x = fmaxf(o0.x, 0.f); o0.y = fmaxf(o0.y, 0.f);
        o0.z = fmaxf(o0.z, 0.f); o0.w = fmaxf(o0.w, 0.f);
        o1.x = fmaxf(o1.x, 0.f); o1.y = fmaxf(o1.y, 0.f);
        o1.z = fmaxf(o1.z, 0.f); o1.w = fmaxf(o1.w, 0.f);
    }
    union { __half2 h2[4]; float4 f; } pk;
    pk.h2[0] = __floats2half2_rn(o0.x, o0.y);
    pk.h2[1] = __floats2half2_rn(o0.z, o0.w);
    pk.h2[2] = __floats2half2_rn(o1.x, o1.y);
    pk.h2[3] = __floats2half2_rn(o1.z, o1.w);
    xout16[(size_t)d * 16 + gl] = pk.f;
}

// ---------------- global mean pool over fp16 x (batch is sorted) ------------
__global__ __launch_bounds__(512) void k_pool(const __half* __restrict__ x,
                                              const int* __restrict__ batch,
                                              float* __restrict__ out) {
    __shared__ float red[512];
    __shared__ int sh[2];
    int g = blockIdx.x;
    int t = threadIdx.x;
    if (t == 0) {
        int lo = 0, hi = N_NODES;
        while (lo < hi) { int mid = (lo + hi) >> 1; if (batch[mid] < g) lo = mid + 1; else hi = mid; }
        sh[0] = lo;
        int lo2 = lo, hi2 = N_NODES;
        while (lo2 < hi2) { int mid = (lo2 + hi2) >> 1; if (batch[mid] < g + 1) lo2 = mid + 1; else hi2 = mid; }
        sh[1] = lo2;
    }
    __syncthreads();
    int lo = sh[0], hi = sh[1];
    int sub = t >> 7, dim = t & 127;
    float sum = 0.f;
    for (int i = lo + sub; i < hi; i += 4) sum += __half2float(x[(size_t)i * 128 + dim]);
    red[t] = sum;
    __syncthreads();
    if (t < 128) {
        float s = red[t] + red[t + 128] + red[t + 256] + red[t + 384];
        int cnt = hi - lo;
        out[g * 128 + t] = s * (cnt > 0 ? 1.f / (float)cnt : 1.f);
    }
}

extern "C" void kernel_launch(void* const* d_in, const int* in_sizes, int n_in,
                              void* d_out, int out_size, void* d_ws, size_t ws_size,
                              hipStream_t stream) {
    const int*   node_ids   = (const int*)d_in[0];
    const int*   edge_index = (const int*)d_in[1];   // [2][800000]
    const int*   batch      = (const int*)d_in[2];
    const float* emb        = (const float*)d_in[3];
    const float* W[3]  = {(const float*)d_in[4],  (const float*)d_in[8],  (const float*)d_in[12]};
    const float* As[3] = {(const float*)d_in[5],  (const float*)d_in[9],  (const float*)d_in[13]};
    const float* Ad[3] = {(const float*)d_in[6],  (const float*)d_in[10], (const float*)d_in[14]};
    const float* Bs[3] = {(const float*)d_in[7],  (const float*)d_in[11], (const float*)d_in[15]};

    char* ws = (char*)d_ws;
    size_t off = 0;
    auto alloc = [&](size_t bytes) {
        void* p = ws + off; off += (bytes + 255) & ~(size_t)255; return p;
    };
    _Float16* xH     = (_Float16*)alloc((size_t)N_NODES * 128 * 2);  // activations (fp16)
    _Float16* hH     = (_Float16*)alloc((size_t)N_NODES * 128 * 2);  // h gather table (fp16)
    float*  as_     = (float*)alloc((size_t)N_NODES * 4);
    float*  ad_     = (float*)alloc((size_t)N_NODES * 4);
    int*    gbins   = (int*)alloc((size_t)NBINS * 4);        // zeroed (adjacent with gcur)
    int*    gcur    = (int*)alloc((size_t)NBINS * 4);        // zeroed
    int*    cbase   = (int*)alloc((size_t)(NBINS + 1) * 4);
    int*    row_ptr = (int*)alloc((size_t)(N_NODES + 1) * 4);
    int*    recs    = (int*)alloc((size_t)N_EDGES * 4);
    int*    srcs    = (int*)alloc((size_t)N_EDGES * 4);
    (void)ws_size; (void)in_sizes; (void)n_in; (void)out_size;

    // zero gbins+gcur in one small memset (adjacent, incl. 256B alloc pad)
    hipMemsetAsync(gbins, 0, (size_t)((char*)cbase - (char*)gbins), stream);

    // multisplit CSR build by dst
    k_chist<<<128, 256, 0, stream>>>(edge_index, gbins);
    k_cscan<<<1, 256, 0, stream>>>(gbins, cbase, row_ptr);
    k_scat1<<<(N_EDGES + 1023) / 1024, 256, 0, stream>>>(edge_index, cbase, gcur, recs);
    k_scat2<<<NB_COARSE, 256, 0, stream>>>(recs, cbase, row_ptr, srcs);

    int gemm_blocks = (N_NODES + 127) / 128;   // 391
    for (int l = 0; l < 3; l++) {
        k_gemm<<<gemm_blocks, 256, 0, stream>>>(
                 (l == 0) ? (const void*)emb : (const void*)xH,
                 (l == 0) ? node_ids : nullptr,
                 W[l], As[l], Ad[l], hH, as_, ad_);
        k_aggregate<<<(N_NODES * 16 + 255) / 256, 256, 0, stream>>>((const float4*)hH,
                 as_, ad_, row_ptr, srcs, (const float4*)Bs[l], (float4*)xH,
                 (l < 2) ? 1 : 0);
    }
    k_pool<<<N_GRAPHS, 512, 0, stream>>>((const __half*)xH, batch, (float*)d_out);
}

// Round 9
// 303.070 us; speedup vs baseline: 1.6501x; 1.0078x over previous
//
#include <hip/hip_runtime.h>
#include <hip/hip_fp16.h>
#include <math.h>

#define N_NODES    50000
#define N_EDGES_IN 800000
#define N_EDGES    850000   // + self loops
#define N_GRAPHS   512
#define NEG_SLOPE  0.2f
#define EPS_F      1e-16f

#define NB_COARSE  196              // ceil(50000/256) coarse dst buckets
#define NSUB       8                // sub-cursors per bucket (contention spread)
#define NBINS      (NB_COARSE*NSUB) // 1568
#define GEMM_BLOCKS 391             // (N_NODES+127)/128
#define HIST_BLOCKS 256

typedef _Float16 half8 __attribute__((ext_vector_type(8)));
typedef float    f32x4 __attribute__((ext_vector_type(4)));

// ---------------- MFMA GEMM + (layer-0) fused coarse histogram --------------
// GEMM role (blocks < GEMM_BLOCKS): 128x128 tile, 256 thr = 4 waves (R7 struct).
// Hist role (layer 0 only, blocks >= GEMM_BLOCKS): coarse dst histogram into
// gbins, reusing the GEMM's LDS as the private histogram.
__global__ __launch_bounds__(256) void k_gemm(const void* __restrict__ xsrc,
                                              const int* __restrict__ ids,
                                              const float* __restrict__ W,
                                              const float* __restrict__ a_s,
                                              const float* __restrict__ a_d,
                                              _Float16* __restrict__ hH,
                                              float* __restrict__ as_,
                                              float* __restrict__ ad_,
                                              const int* __restrict__ ei,
                                              int* __restrict__ gbins) {
    __shared__ _Float16 WT[128][136];   // [n][k] (34.8 KB; hist overlays ints here)
    __shared__ _Float16 Xs[128][72];    // [row][k within chunk]
    int t = threadIdx.x;

    if (gbins != nullptr && blockIdx.x >= GEMM_BLOCKS) {
        // ---- histogram role ----
        int* lh = (int*)&WT[0][0];      // 6.3 KB needed, 34.8 KB available
        for (int i = t; i < NBINS; i += 256) lh[i] = 0;
        __syncthreads();
        int hb = blockIdx.x - GEMM_BLOCKS;   // 0..HIST_BLOCKS-1
        for (int e = hb * 256 + t; e < N_EDGES; e += HIST_BLOCKS * 256) {
            int d = (e < N_EDGES_IN) ? ei[N_EDGES_IN + e] : (e - N_EDGES_IN);
            atomicAdd(&lh[(d >> 8) * NSUB + ((e >> 10) & 7)], 1);
        }
        __syncthreads();
        for (int i = t; i < NBINS; i += 256) {
            int v = lh[i];
            if (v) atomicAdd(&gbins[i], v);
        }
        return;
    }

    // ---- GEMM role ----
    int row0 = blockIdx.x * 128;
    int w = t >> 6, lane = t & 63;
    int n = lane & 15, quad = lane >> 4;

    #pragma unroll
    for (int i = 0; i < 16; i++) {
        int q = t + i * 256;
        int k = q >> 5;
        int n4 = (q & 31) * 4;
        float4 v = *(const float4*)(W + (size_t)k * 128 + n4);
        WT[n4 + 0][k] = (_Float16)v.x;
        WT[n4 + 1][k] = (_Float16)v.y;
        WT[n4 + 2][k] = (_Float16)v.z;
        WT[n4 + 3][k] = (_Float16)v.w;
    }

    f32x4 acc[2][8] = {};
    for (int kc = 0; kc < 2; kc++) {
        if (kc) __syncthreads();
        if (ids == nullptr) {
            const _Float16* xH = (const _Float16*)xsrc;
            #pragma unroll
            for (int i = 0; i < 4; i++) {
                int q = t + i * 256;
                int r = q >> 3, o8 = (q & 7) * 8;
                int gr = row0 + r; if (gr >= N_NODES) gr = N_NODES - 1;
                *(half8*)&Xs[r][o8] = *(const half8*)&xH[(size_t)gr * 128 + kc * 64 + o8];
            }
        } else {
            const float* xf = (const float*)xsrc;
            #pragma unroll
            for (int i = 0; i < 4; i++) {
                int q = t + i * 256;
                int r = q >> 3, o8 = (q & 7) * 8;
                int gr = row0 + r; if (gr >= N_NODES) gr = N_NODES - 1;
                const float* src = xf + (size_t)ids[gr] * 128 + kc * 64 + o8;
                float4 v0 = *(const float4*)src;
                float4 v1 = *(const float4*)(src + 4);
                half8 hv;
                hv[0] = (_Float16)v0.x; hv[1] = (_Float16)v0.y;
                hv[2] = (_Float16)v0.z; hv[3] = (_Float16)v0.w;
                hv[4] = (_Float16)v1.x; hv[5] = (_Float16)v1.y;
                hv[6] = (_Float16)v1.z; hv[7] = (_Float16)v1.w;
                *(half8*)&Xs[r][o8] = hv;
            }
        }
        __syncthreads();
        #pragma unroll
        for (int ks = 0; ks < 2; ks++) {
            int ko = ks * 32 + quad * 8;
            half8 a0 = *(const half8*)&Xs[w * 32 + n][ko];
            half8 a1 = *(const half8*)&Xs[w * 32 + 16 + n][ko];
            int kg = kc * 64 + ko;
            #pragma unroll
            for (int c = 0; c < 8; c++) {
                half8 b = *(const half8*)&WT[c * 16 + n][kg];
                acc[0][c] = __builtin_amdgcn_mfma_f32_16x16x32_f16(a0, b, acc[0][c], 0, 0, 0);
                acc[1][c] = __builtin_amdgcn_mfma_f32_16x16x32_f16(a1, b, acc[1][c], 0, 0, 0);
            }
        }
    }

    float sa[8], da[8];
    #pragma unroll
    for (int c = 0; c < 8; c++) { sa[c] = a_s[c * 16 + n]; da[c] = a_d[c * 16 + n]; }
    #pragma unroll
    for (int r = 0; r < 2; r++) {
        float ps[4] = {0.f, 0.f, 0.f, 0.f}, pd[4] = {0.f, 0.f, 0.f, 0.f};
        #pragma unroll
        for (int reg = 0; reg < 4; reg++) {
            int row = row0 + w * 32 + r * 16 + quad * 4 + reg;
            bool ok = row < N_NODES;
            #pragma unroll
            for (int c = 0; c < 8; c++) {
                float v = acc[r][c][reg];
                ps[reg] += v * sa[c];
                pd[reg] += v * da[c];
                if (ok) hH[(size_t)row * 128 + c * 16 + n] = (_Float16)v;
            }
        }
        #pragma unroll
        for (int off = 1; off < 16; off <<= 1) {
            #pragma unroll
            for (int reg = 0; reg < 4; reg++) {
                ps[reg] += __shfl_xor(ps[reg], off, 64);
                pd[reg] += __shfl_xor(pd[reg], off, 64);
            }
        }
        if (n == 0) {
            #pragma unroll
            for (int reg = 0; reg < 4; reg++) {
                int row = row0 + w * 32 + r * 16 + quad * 4 + reg;
                if (row < N_NODES) { as_[row] = ps[reg]; ad_[row] = pd[reg]; }
            }
        }
    }
}

// exclusive scan of gbins[NBINS] -> cbase[NBINS+1]; also row_ptr[N_NODES]=N_EDGES
__global__ __launch_bounds__(256) void k_cscan(const int* __restrict__ gbins,
                                               int* __restrict__ cbase,
                                               int* __restrict__ row_ptr) {
    __shared__ int part[256];
    int t = threadIdx.x;
    int base = t * 7;                     // 256*7 = 1792 >= 1568
    int lv[7];
    int sum = 0;
    #pragma unroll
    for (int i = 0; i < 7; i++) {
        int idx = base + i;
        int v = (idx < NBINS) ? gbins[idx] : 0;
        lv[i] = sum; sum += v;
    }
    part[t] = sum; __syncthreads();
    for (int off = 1; off < 256; off <<= 1) {
        int x = (t >= off) ? part[t - off] : 0;
        __syncthreads(); part[t] += x; __syncthreads();
    }
    int excl = part[t] - sum;
    #pragma unroll
    for (int i = 0; i < 7; i++) {
        int idx = base + i;
        if (idx < NBINS) cbase[idx] = excl + lv[i];
    }
    if (t == 0) { cbase[NBINS] = N_EDGES; row_ptr[N_NODES] = N_EDGES; }
}

// pass 1: 1024 edges/block; per-(block,bucket) runs written contiguously
__global__ __launch_bounds__(256) void k_scat1(const int* __restrict__ ei,
                                               const int* __restrict__ cbase,
                                               int* __restrict__ gcur,
                                               int* __restrict__ recs) {
    __shared__ int lcnt[NB_COARSE];
    __shared__ int lbase[NB_COARSE];
    int t = threadIdx.x;
    int e0 = blockIdx.x * 1024;
    int sub = blockIdx.x & 7;            // == (e>>10)&7 for all e in this block
    for (int i = t; i < NB_COARSE; i += 256) lcnt[i] = 0;
    __syncthreads();
    int s[4], d[4], b[4], r[4];
    #pragma unroll
    for (int i = 0; i < 4; i++) {
        int e = e0 + t + i * 256;
        if (e < N_EDGES) {
            if (e < N_EDGES_IN) { s[i] = ei[e]; d[i] = ei[N_EDGES_IN + e]; }
            else                { s[i] = e - N_EDGES_IN; d[i] = s[i]; }
            b[i] = d[i] >> 8;
            r[i] = atomicAdd(&lcnt[b[i]], 1);
        } else b[i] = -1;
    }
    __syncthreads();
    for (int i = t; i < NB_COARSE; i += 256) {
        int c = lcnt[i];
        lbase[i] = c ? (cbase[i * NSUB + sub] + atomicAdd(&gcur[i * NSUB + sub], c)) : 0;
    }
    __syncthreads();
    #pragma unroll
    for (int i = 0; i < 4; i++)
        if (b[i] >= 0) recs[lbase[b[i]] + r[i]] = s[i] | ((d[i] & 255) << 16);
}

// pass 2: one block per coarse bucket; fine hist+scan in LDS; all writes land
// in the block's own contiguous region -> full-line writebacks.
__global__ __launch_bounds__(256) void k_scat2(const int* __restrict__ recs,
                                               const int* __restrict__ cbase,
                                               int* __restrict__ row_ptr,
                                               int* __restrict__ srcs) {
    __shared__ int hist[256];
    __shared__ int off[256];
    __shared__ int rank[256];
    int b = blockIdx.x;
    int t = threadIdx.x;
    int lo = cbase[b * NSUB];
    int hi = cbase[(b + 1) * NSUB];
    int cnt = hi - lo;
    hist[t] = 0; rank[t] = 0;
    __syncthreads();
    for (int i = t; i < cnt; i += 256) atomicAdd(&hist[recs[lo + i] >> 16], 1);
    __syncthreads();
    int v = hist[t];
    off[t] = v; __syncthreads();
    for (int o = 1; o < 256; o <<= 1) {
        int x = (t >= o) ? off[t - o] : 0;
        __syncthreads(); off[t] += x; __syncthreads();
    }
    int excl = off[t] - v;
    int dglob = b * 256 + t;
    if (dglob < N_NODES) row_ptr[dglob] = lo + excl;
    __syncthreads();
    off[t] = excl;
    __syncthreads();
    for (int i = t; i < cnt; i += 256) {
        int rec = recs[lo + i];
        int dl = rec >> 16;
        int rk = atomicAdd(&rank[dl], 1);
        srcs[lo + off[dl] + rk] = rec & 0xFFFF;
    }
}

// ---------------- softmax + weighted aggregation, 16 lanes per dst ----------
// srcs is a no-reuse stream -> nontemporal loads keep h-table lines in L2.
__global__ __launch_bounds__(256) void k_aggregate(
        const float4* __restrict__ h16,
        const float* __restrict__ as_,
        const float* __restrict__ ad_, const int* __restrict__ row_ptr,
        const int* __restrict__ srcs, const float4* __restrict__ bias4,
        float4* __restrict__ xout16, int do_relu) {
    int d = (blockIdx.x * blockDim.x + threadIdx.x) >> 4;
    if (d >= N_NODES) return;
    int lane = threadIdx.x & 63;
    int gl   = lane & 15;
    int base = lane & 48;
    int lo = row_ptr[d], hi = row_ptr[d + 1];
    int deg = hi - lo;             // >= 1 (self-loop)
    float add = ad_[d];

    float eC[4]; int sC[4];
    float m_l = -1e30f, s_l = 0.f;
    #pragma unroll
    for (int c = 0; c < 4; c++) {
        float e = -1e30f; int sidx = 0;
        int j = c * 16 + gl;
        if (j < deg) {
            sidx = __builtin_nontemporal_load(&srcs[lo + j]);
            e = as_[sidx] + add;
            e = (e > 0.f) ? e : NEG_SLOPE * e;
            float nm = fmaxf(m_l, e);
            s_l = s_l * __expf(m_l - nm) + __expf(e - nm);
            m_l = nm;
        }
        eC[c] = e; sC[c] = sidx;
    }
    for (int j0 = 64; j0 < deg; j0 += 16) {
        int j = j0 + gl;
        if (j < deg) {
            int sidx = __builtin_nontemporal_load(&srcs[lo + j]);
            float e = as_[sidx] + add;
            e = (e > 0.f) ? e : NEG_SLOPE * e;
            float nm = fmaxf(m_l, e);
            s_l = s_l * __expf(m_l - nm) + __expf(e - nm);
            m_l = nm;
        }
    }
    float m = m_l, s = s_l;
    #pragma unroll
    for (int off = 8; off; off >>= 1) {
        float om = __shfl_xor(m, off, 64);
        float os = __shfl_xor(s, off, 64);
        float nm = fmaxf(m, om);
        s = s * __expf(m - nm) + os * __expf(om - nm);
        m = nm;
    }
    float inv = 1.f / (s + EPS_F);

    float4 acc0 = make_float4(0.f, 0.f, 0.f, 0.f);
    float4 acc1 = make_float4(0.f, 0.f, 0.f, 0.f);
    #pragma unroll
    for (int c = 0; c < 4; c++) {
        int j0 = c * 16;
        if (j0 >= deg) break;
        float w = __expf(eC[c] - m) * inv;
        int sidx = sC[c];
        int cnt = min(16, deg - j0);
        for (int jj = 0; jj < cnt; jj += 4) {
            float w0 = __shfl(w, base + jj + 0, 64); int s0 = __shfl(sidx, base + jj + 0, 64);
            float w1 = __shfl(w, base + jj + 1, 64); int s1 = __shfl(sidx, base + jj + 1, 64);
            float w2 = __shfl(w, base + jj + 2, 64); int s2 = __shfl(sidx, base + jj + 2, 64);
            float w3 = __shfl(w, base + jj + 3, 64); int s3 = __shfl(sidx, base + jj + 3, 64);
            float4 r0 = h16[(size_t)s0 * 16 + gl];
            float4 r1 = h16[(size_t)s1 * 16 + gl];
            float4 r2 = h16[(size_t)s2 * 16 + gl];
            float4 r3 = h16[(size_t)s3 * 16 + gl];
            const __half2* p;
            float2 f0, f1, f2, f3;
            p = (const __half2*)&r0;
            f0 = __half22float2(p[0]); f1 = __half22float2(p[1]);
            f2 = __half22float2(p[2]); f3 = __half22float2(p[3]);
            acc0.x += w0*f0.x; acc0.y += w0*f0.y; acc0.z += w0*f1.x; acc0.w += w0*f1.y;
            acc1.x += w0*f2.x; acc1.y += w0*f2.y; acc1.z += w0*f3.x; acc1.w += w0*f3.y;
            p = (const __half2*)&r1;
            f0 = __half22float2(p[0]); f1 = __half22float2(p[1]);
            f2 = __half22float2(p[2]); f3 = __half22float2(p[3]);
            acc0.x += w1*f0.x; acc0.y += w1*f0.y; acc0.z += w1*f1.x; acc0.w += w1*f1.y;
            acc1.x += w1*f2.x; acc1.y += w1*f2.y; acc1.z += w1*f3.x; acc1.w += w1*f3.y;
            p = (const __half2*)&r2;
            f0 = __half22float2(p[0]); f1 = __half22float2(p[1]);
            f2 = __half22float2(p[2]); f3 = __half22float2(p[3]);
            acc0.x += w2*f0.x; acc0.y += w2*f0.y; acc0.z += w2*f1.x; acc0.w += w2*f1.y;
            acc1.x += w2*f2.x; acc1.y += w2*f2.y; acc1.z += w2*f3.x; acc1.w += w2*f3.y;
            p = (const __half2*)&r3;
            f0 = __half22float2(p[0]); f1 = __half22float2(p[1]);
            f2 = __half22float2(p[2]); f3 = __half22float2(p[3]);
            acc0.x += w3*f0.x; acc0.y += w3*f0.y; acc0.z += w3*f1.x; acc0.w += w3*f1.y;
            acc1.x += w3*f2.x; acc1.y += w3*f2.y; acc1.z += w3*f3.x; acc1.w += w3*f3.y;
        }
    }
    for (int j0 = 64; j0 < deg; j0 += 16) {
        int j = j0 + gl;
        float w = 0.f; int sidx = 0;
        if (j < deg) {
            int si = __builtin_nontemporal_load(&srcs[lo + j]);
            float e = as_[si] + add;
            e = (e > 0.f) ? e : NEG_SLOPE * e;
            w = __expf(e - m) * inv;
            sidx = si;
        }
        int cnt = min(16, deg - j0);
        for (int jj = 0; jj < cnt; jj++) {
            float w0 = __shfl(w, base + jj, 64); int s0 = __shfl(sidx, base + jj, 64);
            float4 r0 = h16[(size_t)s0 * 16 + gl];
            const __half2* p = (const __half2*)&r0;
            float2 f0 = __half22float2(p[0]), f1 = __half22float2(p[1]);
            float2 f2 = __half22float2(p[2]), f3 = __half22float2(p[3]);
            acc0.x += w0*f0.x; acc0.y += w0*f0.y; acc0.z += w0*f1.x; acc0.w += w0*f1.y;
            acc1.x += w0*f2.x; acc1.y += w0*f2.y; acc1.z += w0*f3.x; acc1.w += w0*f3.y;
        }
    }
    float4 b0 = bias4[gl * 2], b1 = bias4[gl * 2 + 1];
    float4 o0 = make_float4(acc0.x + b0.x, acc0.y + b0.y, acc0.z + b0.z, acc0.w + b0.w);
    float4 o1 = make_float4(acc1.x + b1.x, acc1.y + b1.y, acc1.z + b1.z, acc1.w + b1.w);
    if (do_relu) {
        o0.x = fmaxf(o0.x, 0.f); o0.y = fmaxf(o0.y, 0.f);
        o0.z = fmaxf(o0.z, 0.f); o0.w = fmaxf(o0.w, 0.f);
        o1.x = fmaxf(o1.x, 0.f); o1.y = fmaxf(o1.y, 0.f);
        o1.z = fmaxf(o1.z, 0.f); o1.w = fmaxf(o1.w, 0.f);
    }
    union { __half2 h2[4]; float4 f; } pk;
    pk.h2[0] = __floats2half2_rn(o0.x, o0.y);
    pk.h2[1] = __floats2half2_rn(o0.z, o0.w);
    pk.h2[2] = __floats2half2_rn(o1.x, o1.y);
    pk.h2[3] = __floats2half2_rn(o1.z, o1.w);
    xout16[(size_t)d * 16 + gl] = pk.f;
}

// ---------------- global mean pool over fp16 x (batch is sorted) ------------
__global__ __launch_bounds__(512) void k_pool(const __half* __restrict__ x,
                                              const int* __restrict__ batch,
                                              float* __restrict__ out) {
    __shared__ float red[512];
    __shared__ int sh[2];
    int g = blockIdx.x;
    int t = threadIdx.x;
    if (t == 0) {
        int lo = 0, hi = N_NODES;
        while (lo < hi) { int mid = (lo + hi) >> 1; if (batch[mid] < g) lo = mid + 1; else hi = mid; }
        sh[0] = lo;
        int lo2 = lo, hi2 = N_NODES;
        while (lo2 < hi2) { int mid = (lo2 + hi2) >> 1; if (batch[mid] < g + 1) lo2 = mid + 1; else hi2 = mid; }
        sh[1] = lo2;
    }
    __syncthreads();
    int lo = sh[0], hi = sh[1];
    int sub = t >> 7, dim = t & 127;
    float sum = 0.f;
    for (int i = lo + sub; i < hi; i += 4) sum += __half2float(x[(size_t)i * 128 + dim]);
    red[t] = sum;
    __syncthreads();
    if (t < 128) {
        float s = red[t] + red[t + 128] + red[t + 256] + red[t + 384];
        int cnt = hi - lo;
        out[g * 128 + t] = s * (cnt > 0 ? 1.f / (float)cnt : 1.f);
    }
}

extern "C" void kernel_launch(void* const* d_in, const int* in_sizes, int n_in,
                              void* d_out, int out_size, void* d_ws, size_t ws_size,
                              hipStream_t stream) {
    const int*   node_ids   = (const int*)d_in[0];
    const int*   edge_index = (const int*)d_in[1];   // [2][800000]
    const int*   batch      = (const int*)d_in[2];
    const float* emb        = (const float*)d_in[3];
    const float* W[3]  = {(const float*)d_in[4],  (const float*)d_in[8],  (const float*)d_in[12]};
    const float* As[3] = {(const float*)d_in[5],  (const float*)d_in[9],  (const float*)d_in[13]};
    const float* Ad[3] = {(const float*)d_in[6],  (const float*)d_in[10], (const float*)d_in[14]};
    const float* Bs[3] = {(const float*)d_in[7],  (const float*)d_in[11], (const float*)d_in[15]};

    char* ws = (char*)d_ws;
    size_t off = 0;
    auto alloc = [&](size_t bytes) {
        void* p = ws + off; off += (bytes + 255) & ~(size_t)255; return p;
    };
    _Float16* xH    = (_Float16*)alloc((size_t)N_NODES * 128 * 2);  // activations (fp16)
    _Float16* hH    = (_Float16*)alloc((size_t)N_NODES * 128 * 2);  // h gather table (fp16)
    float*  as_     = (float*)alloc((size_t)N_NODES * 4);
    float*  ad_     = (float*)alloc((size_t)N_NODES * 4);
    int*    gbins   = (int*)alloc((size_t)NBINS * 4);        // zeroed (adjacent with gcur)
    int*    gcur    = (int*)alloc((size_t)NBINS * 4);        // zeroed
    int*    cbase   = (int*)alloc((size_t)(NBINS + 1) * 4);
    int*    row_ptr = (int*)alloc((size_t)(N_NODES + 1) * 4);
    int*    recs    = (int*)alloc((size_t)N_EDGES * 4);
    int*    srcs    = (int*)alloc((size_t)N_EDGES * 4);
    (void)ws_size; (void)in_sizes; (void)n_in; (void)out_size;

    // zero gbins+gcur in one small memset (adjacent, incl. 256B alloc pad)
    hipMemsetAsync(gbins, 0, (size_t)((char*)cbase - (char*)gbins), stream);

    // layer 0 GEMM with fused coarse histogram (extra HIST_BLOCKS blocks)
    k_gemm<<<GEMM_BLOCKS + HIST_BLOCKS, 256, 0, stream>>>(
             (const void*)emb, node_ids, W[0], As[0], Ad[0], hH, as_, ad_,
             edge_index, gbins);
    // finish CSR build (needed before aggregate 0)
    k_cscan<<<1, 256, 0, stream>>>(gbins, cbase, row_ptr);
    k_scat1<<<(N_EDGES + 1023) / 1024, 256, 0, stream>>>(edge_index, cbase, gcur, recs);
    k_scat2<<<NB_COARSE, 256, 0, stream>>>(recs, cbase, row_ptr, srcs);

    for (int l = 0; l < 3; l++) {
        if (l) {
            k_gemm<<<GEMM_BLOCKS, 256, 0, stream>>>(
                     (const void*)xH, nullptr, W[l], As[l], Ad[l], hH, as_, ad_,
                     nullptr, nullptr);
        }
        k_aggregate<<<(N_NODES * 16 + 255) / 256, 256, 0, stream>>>((const float4*)hH,
                 as_, ad_, row_ptr, srcs, (const float4*)Bs[l], (float4*)xH,
                 (l < 2) ? 1 : 0);
    }
    k_pool<<<N_GRAPHS, 512, 0, stream>>>((const __half*)xH, batch, (float*)d_out);
}

// Round 10
// 293.470 us; speedup vs baseline: 1.7041x; 1.0327x over previous
//
#include <hip/hip_runtime.h>
#include <hip/hip_fp16.h>
#include <math.h>

#define N_NODES    50000
#define N_EDGES_IN 800000
#define N_EDGES    850000   // + self loops
#define N_GRAPHS   512
#define NEG_SLOPE  0.2f
#define EPS_F      1e-16f

#define NB_COARSE  196              // ceil(50000/256) coarse dst buckets
#define NSUB       8                // sub-regions per bucket (writer spread)
#define NBINS      (NB_COARSE*NSUB) // 1568
#define CAP        1024             // slots per (bucket,sub) region; max load ~810
#define GEMM_BLOCKS 391             // (N_NODES+127)/128

typedef _Float16 half8 __attribute__((ext_vector_type(8)));
typedef float    f32x4 __attribute__((ext_vector_type(4)));

// ---------------- MFMA GEMM: h[N,128] = x[N,128] @ W[128,128] + fused scores
// 128x128 tile, 256 thr = 4 waves (R7 structure, verified).
__global__ __launch_bounds__(256) void k_gemm(const void* __restrict__ xsrc,
                                              const int* __restrict__ ids,
                                              const float* __restrict__ W,
                                              const float* __restrict__ a_s,
                                              const float* __restrict__ a_d,
                                              _Float16* __restrict__ hH,
                                              float* __restrict__ as_,
                                              float* __restrict__ ad_) {
    __shared__ _Float16 WT[128][136];   // [n][k]
    __shared__ _Float16 Xs[128][72];    // [row][k within chunk]
    int t = threadIdx.x;
    int row0 = blockIdx.x * 128;
    int w = t >> 6, lane = t & 63;
    int n = lane & 15, quad = lane >> 4;

    #pragma unroll
    for (int i = 0; i < 16; i++) {
        int q = t + i * 256;
        int k = q >> 5;
        int n4 = (q & 31) * 4;
        float4 v = *(const float4*)(W + (size_t)k * 128 + n4);
        WT[n4 + 0][k] = (_Float16)v.x;
        WT[n4 + 1][k] = (_Float16)v.y;
        WT[n4 + 2][k] = (_Float16)v.z;
        WT[n4 + 3][k] = (_Float16)v.w;
    }

    f32x4 acc[2][8] = {};
    for (int kc = 0; kc < 2; kc++) {
        if (kc) __syncthreads();
        if (ids == nullptr) {
            const _Float16* xH = (const _Float16*)xsrc;
            #pragma unroll
            for (int i = 0; i < 4; i++) {
                int q = t + i * 256;
                int r = q >> 3, o8 = (q & 7) * 8;
                int gr = row0 + r; if (gr >= N_NODES) gr = N_NODES - 1;
                *(half8*)&Xs[r][o8] = *(const half8*)&xH[(size_t)gr * 128 + kc * 64 + o8];
            }
        } else {
            const float* xf = (const float*)xsrc;
            #pragma unroll
            for (int i = 0; i < 4; i++) {
                int q = t + i * 256;
                int r = q >> 3, o8 = (q & 7) * 8;
                int gr = row0 + r; if (gr >= N_NODES) gr = N_NODES - 1;
                const float* src = xf + (size_t)ids[gr] * 128 + kc * 64 + o8;
                float4 v0 = *(const float4*)src;
                float4 v1 = *(const float4*)(src + 4);
                half8 hv;
                hv[0] = (_Float16)v0.x; hv[1] = (_Float16)v0.y;
                hv[2] = (_Float16)v0.z; hv[3] = (_Float16)v0.w;
                hv[4] = (_Float16)v1.x; hv[5] = (_Float16)v1.y;
                hv[6] = (_Float16)v1.z; hv[7] = (_Float16)v1.w;
                *(half8*)&Xs[r][o8] = hv;
            }
        }
        __syncthreads();
        #pragma unroll
        for (int ks = 0; ks < 2; ks++) {
            int ko = ks * 32 + quad * 8;
            half8 a0 = *(const half8*)&Xs[w * 32 + n][ko];
            half8 a1 = *(const half8*)&Xs[w * 32 + 16 + n][ko];
            int kg = kc * 64 + ko;
            #pragma unroll
            for (int c = 0; c < 8; c++) {
                half8 b = *(const half8*)&WT[c * 16 + n][kg];
                acc[0][c] = __builtin_amdgcn_mfma_f32_16x16x32_f16(a0, b, acc[0][c], 0, 0, 0);
                acc[1][c] = __builtin_amdgcn_mfma_f32_16x16x32_f16(a1, b, acc[1][c], 0, 0, 0);
            }
        }
    }

    float sa[8], da[8];
    #pragma unroll
    for (int c = 0; c < 8; c++) { sa[c] = a_s[c * 16 + n]; da[c] = a_d[c * 16 + n]; }
    #pragma unroll
    for (int r = 0; r < 2; r++) {
        float ps[4] = {0.f, 0.f, 0.f, 0.f}, pd[4] = {0.f, 0.f, 0.f, 0.f};
        #pragma unroll
        for (int reg = 0; reg < 4; reg++) {
            int row = row0 + w * 32 + r * 16 + quad * 4 + reg;
            bool ok = row < N_NODES;
            #pragma unroll
            for (int c = 0; c < 8; c++) {
                float v = acc[r][c][reg];
                ps[reg] += v * sa[c];
                pd[reg] += v * da[c];
                if (ok) hH[(size_t)row * 128 + c * 16 + n] = (_Float16)v;
            }
        }
        #pragma unroll
        for (int off = 1; off < 16; off <<= 1) {
            #pragma unroll
            for (int reg = 0; reg < 4; reg++) {
                ps[reg] += __shfl_xor(ps[reg], off, 64);
                pd[reg] += __shfl_xor(pd[reg], off, 64);
            }
        }
        if (n == 0) {
            #pragma unroll
            for (int reg = 0; reg < 4; reg++) {
                int row = row0 + w * 32 + r * 16 + quad * 4 + reg;
                if (row < N_NODES) { as_[row] = ps[reg]; ad_[row] = pd[reg]; }
            }
        }
    }
}

// ---------------- CSR build, 2 kernels, fixed-capacity regions --------------
// pass 1: 4096 edges/block; per-(block,bucket) runs appended contiguously into
// region (bucket*NSUB+sub)*CAP via one global cursor bump per bucket per block.
__global__ __launch_bounds__(256) void k_scat1(const int* __restrict__ ei,
                                               int* __restrict__ gcur,
                                               int* __restrict__ recs) {
    __shared__ int lcnt[NB_COARSE];
    __shared__ int lbase[NB_COARSE];
    int t = threadIdx.x;
    int e0 = blockIdx.x * 4096;
    int sub = blockIdx.x & 7;
    for (int i = t; i < NB_COARSE; i += 256) lcnt[i] = 0;
    __syncthreads();
    int rec[16], b[16], r[16];
    #pragma unroll
    for (int i = 0; i < 16; i++) {
        int e = e0 + t + i * 256;
        if (e < N_EDGES) {
            int s, d;
            if (e < N_EDGES_IN) { s = ei[e]; d = ei[N_EDGES_IN + e]; }
            else                { s = e - N_EDGES_IN; d = s; }
            b[i] = d >> 8;
            rec[i] = s | ((d & 255) << 16);
            r[i] = atomicAdd(&lcnt[b[i]], 1);
        } else b[i] = -1;
    }
    __syncthreads();
    for (int i = t; i < NB_COARSE; i += 256) {
        int c = lcnt[i];
        lbase[i] = c ? atomicAdd(&gcur[i * NSUB + sub], c) : 0;
    }
    __syncthreads();
    #pragma unroll
    for (int i = 0; i < 16; i++)
        if (b[i] >= 0) recs[(b[i] * NSUB + sub) * CAP + lbase[b[i]] + r[i]] = rec[i];
}

// pass 2: one block per coarse bucket. Computes its global base from the final
// cursors (no separate scan kernel), fine-sorts by dst, writes row_ptr + srcs.
__global__ __launch_bounds__(256) void k_scat2(const int* __restrict__ recs,
                                               const int* __restrict__ gcur,
                                               int* __restrict__ row_ptr,
                                               int* __restrict__ srcs) {
    __shared__ int scnt[NBINS];     // final per-(bucket,sub) counts
    __shared__ int bcnt[256];       // per-bucket totals -> inclusive scan
    __shared__ int hist[256];
    __shared__ int off2[256];
    __shared__ int rank[256];
    int b = blockIdx.x, t = threadIdx.x;
    for (int i = t; i < NBINS; i += 256) scnt[i] = gcur[i];
    hist[t] = 0; rank[t] = 0;
    __syncthreads();
    int tot = 0;
    if (t < NB_COARSE) {
        #pragma unroll
        for (int s = 0; s < NSUB; s++) tot += scnt[t * NSUB + s];
    }
    bcnt[t] = tot;
    __syncthreads();
    for (int o = 1; o < 256; o <<= 1) {
        int x = (t >= o) ? bcnt[t - o] : 0;
        __syncthreads(); bcnt[t] += x; __syncthreads();
    }
    int lo = (b == 0) ? 0 : bcnt[b - 1];
    // fine histogram over this bucket's records
    for (int s = 0; s < NSUB; s++) {
        int c = scnt[b * NSUB + s];
        const int* reg = &recs[(b * NSUB + s) * CAP];
        for (int i = t; i < c; i += 256) atomicAdd(&hist[reg[i] >> 16], 1);
    }
    __syncthreads();
    int v = hist[t];
    off2[t] = v; __syncthreads();
    for (int o = 1; o < 256; o <<= 1) {
        int x = (t >= o) ? off2[t - o] : 0;
        __syncthreads(); off2[t] += x; __syncthreads();
    }
    int excl = off2[t] - v;
    int dglob = b * 256 + t;
    if (dglob < N_NODES) row_ptr[dglob] = lo + excl;
    if (b == 0 && t == 0) row_ptr[N_NODES] = N_EDGES;
    __syncthreads();
    off2[t] = excl;
    __syncthreads();
    for (int s = 0; s < NSUB; s++) {
        int c = scnt[b * NSUB + s];
        const int* reg = &recs[(b * NSUB + s) * CAP];
        for (int i = t; i < c; i += 256) {
            int rec = reg[i];
            int dl = rec >> 16;
            int rk = atomicAdd(&rank[dl], 1);
            srcs[lo + off2[dl] + rk] = rec & 0xFFFF;
        }
    }
}

// ---------------- softmax + weighted aggregation, 16 lanes per dst ----------
__global__ __launch_bounds__(256) void k_aggregate(
        const float4* __restrict__ h16,
        const float* __restrict__ as_,
        const float* __restrict__ ad_, const int* __restrict__ row_ptr,
        const int* __restrict__ srcs, const float4* __restrict__ bias4,
        float4* __restrict__ xout16, int do_relu) {
    int d = (blockIdx.x * blockDim.x + threadIdx.x) >> 4;
    if (d >= N_NODES) return;
    int lane = threadIdx.x & 63;
    int gl   = lane & 15;
    int base = lane & 48;
    int lo = row_ptr[d], hi = row_ptr[d + 1];
    int deg = hi - lo;             // >= 1 (self-loop)
    float add = ad_[d];

    float eC[4]; int sC[4];
    float m_l = -1e30f, s_l = 0.f;
    #pragma unroll
    for (int c = 0; c < 4; c++) {
        float e = -1e30f; int sidx = 0;
        int j = c * 16 + gl;
        if (j < deg) {
            sidx = __builtin_nontemporal_load(&srcs[lo + j]);
            e = as_[sidx] + add;
            e = (e > 0.f) ? e : NEG_SLOPE * e;
            float nm = fmaxf(m_l, e);
            s_l = s_l * __expf(m_l - nm) + __expf(e - nm);
            m_l = nm;
        }
        eC[c] = e; sC[c] = sidx;
    }
    for (int j0 = 64; j0 < deg; j0 += 16) {
        int j = j0 + gl;
        if (j < deg) {
            int sidx = __builtin_nontemporal_load(&srcs[lo + j]);
            float e = as_[sidx] + add;
            e = (e > 0.f) ? e : NEG_SLOPE * e;
            float nm = fmaxf(m_l, e);
            s_l = s_l * __expf(m_l - nm) + __expf(e - nm);
            m_l = nm;
        }
    }
    float m = m_l, s = s_l;
    #pragma unroll
    for (int off = 8; off; off >>= 1) {
        float om = __shfl_xor(m, off, 64);
        float os = __shfl_xor(s, off, 64);
        float nm = fmaxf(m, om);
        s = s * __expf(m - nm) + os * __expf(om - nm);
        m = nm;
    }
    float inv = 1.f / (s + EPS_F);

    float4 acc0 = make_float4(0.f, 0.f, 0.f, 0.f);
    float4 acc1 = make_float4(0.f, 0.f, 0.f, 0.f);
    #pragma unroll
    for (int c = 0; c < 4; c++) {
        int j0 = c * 16;
        if (j0 >= deg) break;
        float w = __expf(eC[c] - m) * inv;
        int sidx = sC[c];
        int cnt = min(16, deg - j0);
        for (int jj = 0; jj < cnt; jj += 4) {
            float w0 = __shfl(w, base + jj + 0, 64); int s0 = __shfl(sidx, base + jj + 0, 64);
            float w1 = __shfl(w, base + jj + 1, 64); int s1 = __shfl(sidx, base + jj + 1, 64);
            float w2 = __shfl(w, base + jj + 2, 64); int s2 = __shfl(sidx, base + jj + 2, 64);
            float w3 = __shfl(w, base + jj + 3, 64); int s3 = __shfl(sidx, base + jj + 3, 64);
            float4 r0 = h16[(size_t)s0 * 16 + gl];
            float4 r1 = h16[(size_t)s1 * 16 + gl];
            float4 r2 = h16[(size_t)s2 * 16 + gl];
            float4 r3 = h16[(size_t)s3 * 16 + gl];
            const __half2* p;
            float2 f0, f1, f2, f3;
            p = (const __half2*)&r0;
            f0 = __half22float2(p[0]); f1 = __half22float2(p[1]);
            f2 = __half22float2(p[2]); f3 = __half22float2(p[3]);
            acc0.x += w0*f0.x; acc0.y += w0*f0.y; acc0.z += w0*f1.x; acc0.w += w0*f1.y;
            acc1.x += w0*f2.x; acc1.y += w0*f2.y; acc1.z += w0*f3.x; acc1.w += w0*f3.y;
            p = (const __half2*)&r1;
            f0 = __half22float2(p[0]); f1 = __half22float2(p[1]);
            f2 = __half22float2(p[2]); f3 = __half22float2(p[3]);
            acc0.x += w1*f0.x; acc0.y += w1*f0.y; acc0.z += w1*f1.x; acc0.w += w1*f1.y;
            acc1.x += w1*f2.x; acc1.y += w1*f2.y; acc1.z += w1*f3.x; acc1.w += w1*f3.y;
            p = (const __half2*)&r2;
            f0 = __half22float2(p[0]); f1 = __half22float2(p[1]);
            f2 = __half22float2(p[2]); f3 = __half22float2(p[3]);
            acc0.x += w2*f0.x; acc0.y += w2*f0.y; acc0.z += w2*f1.x; acc0.w += w2*f1.y;
            acc1.x += w2*f2.x; acc1.y += w2*f2.y; acc1.z += w2*f3.x; acc1.w += w2*f3.y;
            p = (const __half2*)&r3;
            f0 = __half22float2(p[0]); f1 = __half22float2(p[1]);
            f2 = __half22float2(p[2]); f3 = __half22float2(p[3]);
            acc0.x += w3*f0.x; acc0.y += w3*f0.y; acc0.z += w3*f1.x; acc0.w += w3*f1.y;
            acc1.x += w3*f2.x; acc1.y += w3*f2.y; acc1.z += w3*f3.x; acc1.w += w3*f3.y;
        }
    }
    for (int j0 = 64; j0 < deg; j0 += 16) {
        int j = j0 + gl;
        float w = 0.f; int sidx = 0;
        if (j < deg) {
            int si = __builtin_nontemporal_load(&srcs[lo + j]);
            float e = as_[si] + add;
            e = (e > 0.f) ? e : NEG_SLOPE * e;
            w = __expf(e - m) * inv;
            sidx = si;
        }
        int cnt = min(16, deg - j0);
        for (int jj = 0; jj < cnt; jj++) {
            float w0 = __shfl(w, base + jj, 64); int s0 = __shfl(sidx, base + jj, 64);
            float4 r0 = h16[(size_t)s0 * 16 + gl];
            const __half2* p = (const __half2*)&r0;
            float2 f0 = __half22float2(p[0]), f1 = __half22float2(p[1]);
            float2 f2 = __half22float2(p[2]), f3 = __half22float2(p[3]);
            acc0.x += w0*f0.x; acc0.y += w0*f0.y; acc0.z += w0*f1.x; acc0.w += w0*f1.y;
            acc1.x += w0*f2.x; acc1.y += w0*f2.y; acc1.z += w0*f3.x; acc1.w += w0*f3.y;
        }
    }
    float4 b0 = bias4[gl * 2], b1 = bias4[gl * 2 + 1];
    float4 o0 = make_float4(acc0.x + b0.x, acc0.y + b0.y, acc0.z + b0.z, acc0.w + b0.w);
    float4 o1 = make_float4(acc1.x + b1.x, acc1.y + b1.y, acc1.z + b1.z, acc1.w + b1.w);
    if (do_relu) {
        o0.x = fmaxf(o0.x, 0.f); o0.y = fmaxf(o0.y, 0.f);
        o0.z = fmaxf(o0.z, 0.f); o0.w = fmaxf(o0.w, 0.f);
        o1.x = fmaxf(o1.x, 0.f); o1.y = fmaxf(o1.y, 0.f);
        o1.z = fmaxf(o1.z, 0.f); o1.w = fmaxf(o1.w, 0.f);
    }
    union { __half2 h2[4]; float4 f; } pk;
    pk.h2[0] = __floats2half2_rn(o0.x, o0.y);
    pk.h2[1] = __floats2half2_rn(o0.z, o0.w);
    pk.h2[2] = __floats2half2_rn(o1.x, o1.y);
    pk.h2[3] = __floats2half2_rn(o1.z, o1.w);
    xout16[(size_t)d * 16 + gl] = pk.f;
}

// ---------------- global mean pool over fp16 x (batch is sorted) ------------
__global__ __launch_bounds__(512) void k_pool(const __half* __restrict__ x,
                                              const int* __restrict__ batch,
                                              float* __restrict__ out) {
    __shared__ float red[512];
    __shared__ int sh[2];
    int g = blockIdx.x;
    int t = threadIdx.x;
    if (t == 0) {
        int lo = 0, hi = N_NODES;
        while (lo < hi) { int mid = (lo + hi) >> 1; if (batch[mid] < g) lo = mid + 1; else hi = mid; }
        sh[0] = lo;
        int lo2 = lo, hi2 = N_NODES;
        while (lo2 < hi2) { int mid = (lo2 + hi2) >> 1; if (batch[mid] < g + 1) lo2 = mid + 1; else hi2 = mid; }
        sh[1] = lo2;
    }
    __syncthreads();
    int lo = sh[0], hi = sh[1];
    int sub = t >> 7, dim = t & 127;
    float sum = 0.f;
    for (int i = lo + sub; i < hi; i += 4) sum += __half2float(x[(size_t)i * 128 + dim]);
    red[t] = sum;
    __syncthreads();
    if (t < 128) {
        float s = red[t] + red[t + 128] + red[t + 256] + red[t + 384];
        int cnt = hi - lo;
        out[g * 128 + t] = s * (cnt > 0 ? 1.f / (float)cnt : 1.f);
    }
}

extern "C" void kernel_launch(void* const* d_in, const int* in_sizes, int n_in,
                              void* d_out, int out_size, void* d_ws, size_t ws_size,
                              hipStream_t stream) {
    const int*   node_ids   = (const int*)d_in[0];
    const int*   edge_index = (const int*)d_in[1];   // [2][800000]
    const int*   batch      = (const int*)d_in[2];
    const float* emb        = (const float*)d_in[3];
    const float* W[3]  = {(const float*)d_in[4],  (const float*)d_in[8],  (const float*)d_in[12]};
    const float* As[3] = {(const float*)d_in[5],  (const float*)d_in[9],  (const float*)d_in[13]};
    const float* Ad[3] = {(const float*)d_in[6],  (const float*)d_in[10], (const float*)d_in[14]};
    const float* Bs[3] = {(const float*)d_in[7],  (const float*)d_in[11], (const float*)d_in[15]};

    char* ws = (char*)d_ws;
    size_t off = 0;
    auto alloc = [&](size_t bytes) {
        void* p = ws + off; off += (bytes + 255) & ~(size_t)255; return p;
    };
    _Float16* xH    = (_Float16*)alloc((size_t)N_NODES * 128 * 2);  // activations (fp16)
    _Float16* hH    = (_Float16*)alloc((size_t)N_NODES * 128 * 2);  // h gather table (fp16)
    float*  as_     = (float*)alloc((size_t)N_NODES * 4);
    float*  ad_     = (float*)alloc((size_t)N_NODES * 4);
    int*    gcur    = (int*)alloc((size_t)NBINS * 4);        // zeroed cursors
    int*    row_ptr = (int*)alloc((size_t)(N_NODES + 1) * 4);
    int*    recs    = (int*)alloc((size_t)NBINS * CAP * 4);  // 6.4 MB fixed regions
    int*    srcs    = (int*)alloc((size_t)N_EDGES * 4);
    (void)ws_size; (void)in_sizes; (void)n_in; (void)out_size;

    hipMemsetAsync(gcur, 0, (size_t)NBINS * 4, stream);

    // CSR build: 2 kernels, fixed-capacity regions (no histogram/scan kernels)
    k_scat1<<<(N_EDGES + 4095) / 4096, 256, 0, stream>>>(edge_index, gcur, recs);
    k_scat2<<<NB_COARSE, 256, 0, stream>>>(recs, gcur, row_ptr, srcs);

    for (int l = 0; l < 3; l++) {
        k_gemm<<<GEMM_BLOCKS, 256, 0, stream>>>(
                 (l == 0) ? (const void*)emb : (const void*)xH,
                 (l == 0) ? node_ids : nullptr,
                 W[l], As[l], Ad[l], hH, as_, ad_);
        k_aggregate<<<(N_NODES * 16 + 255) / 256, 256, 0, stream>>>((const float4*)hH,
                 as_, ad_, row_ptr, srcs, (const float4*)Bs[l], (float4*)xH,
                 (l < 2) ? 1 : 0);
    }
    k_pool<<<N_GRAPHS, 512, 0, stream>>>((const __half*)xH, batch, (float*)d_out);
}